// Round 1
// baseline (677.080 us; speedup 1.0000x reference)
//
#include <hip/hip_runtime.h>
#include <hip/hip_bf16.h>
#include <math.h>

// Problem constants
#define BB 2
#define NN 2048
#define DIM 512
#define NH 8
#define HD 64
#define SCALE 0.125f

// Workspace float offsets
#define OFF_Q    0u
#define OFF_KT   2097152u
#define OFF_V    4194304u
#define OFF_OH   6291456u
#define OFF_RMAX 8388608u
#define OFF_RSUM 8392704u

// ---------------------------------------------------------------------------
// Kernel A: per-row softmax stats of adj  (rmax, rsum) over last axis
// grid = BB*NN blocks, 256 threads
// ---------------------------------------------------------------------------
__global__ __launch_bounds__(256) void adj_stats(const float* __restrict__ adj,
                                                 float* __restrict__ rmax,
                                                 float* __restrict__ rsum) {
    int row = blockIdx.x;                 // b*NN + i
    const float* a = adj + (size_t)row * NN;
    int t = threadIdx.x;
    float v[8];
    float mx = -INFINITY;
#pragma unroll
    for (int c = 0; c < 8; ++c) { v[c] = a[t + 256 * c]; mx = fmaxf(mx, v[c]); }
    __shared__ float red[256];
    red[t] = mx; __syncthreads();
    for (int s = 128; s > 0; s >>= 1) {
        if (t < s) red[t] = fmaxf(red[t], red[t + s]);
        __syncthreads();
    }
    mx = red[0]; __syncthreads();
    float sm = 0.f;
#pragma unroll
    for (int c = 0; c < 8; ++c) sm += __expf(v[c] - mx);
    red[t] = sm; __syncthreads();
    for (int s = 128; s > 0; s >>= 1) {
        if (t < s) red[t] += red[t + s];
        __syncthreads();
    }
    if (t == 0) { rmax[row] = mx; rsum[row] = red[0]; }
}

// ---------------------------------------------------------------------------
// Kernel B: qkv = x @ w_qkv  with scatter into q[b,h,n,d], kT[b,h,d,n], v[b,h,n,d]
// M=BB*NN=4096, K=512, N=1536. 64x64 tiles, 256 threads, 4x4 micro-tile.
// ---------------------------------------------------------------------------
__global__ __launch_bounds__(256) void qkv_gemm(const float* __restrict__ x,
                                                const float* __restrict__ w,
                                                float* __restrict__ q,
                                                float* __restrict__ kT,
                                                float* __restrict__ v) {
    __shared__ __align__(16) float As[16][64];   // [k][m]
    __shared__ __align__(16) float Bs[16][64];   // [k][n]
    int tx = threadIdx.x & 15, ty = threadIdx.x >> 4;
    int m0 = blockIdx.y * 64;
    int n0 = blockIdx.x * 64;
    float acc[4][4] = {};
    for (int k0 = 0; k0 < 512; k0 += 16) {
        for (int l = threadIdx.x; l < 64 * 16; l += 256) {
            int col = l & 15, row = l >> 4;
            As[col][row] = x[(size_t)(m0 + row) * 512 + k0 + col];
        }
        for (int l = threadIdx.x; l < 16 * 64; l += 256) {
            int col = l & 63, row = l >> 6;
            Bs[row][col] = w[(size_t)(k0 + row) * 1536 + n0 + col];
        }
        __syncthreads();
#pragma unroll
        for (int k = 0; k < 16; ++k) {
            float4 a4 = *(const float4*)&As[k][ty * 4];
            float4 b4 = *(const float4*)&Bs[k][tx * 4];
            float av[4] = {a4.x, a4.y, a4.z, a4.w};
            float bv[4] = {b4.x, b4.y, b4.z, b4.w};
#pragma unroll
            for (int r = 0; r < 4; ++r)
#pragma unroll
                for (int c = 0; c < 4; ++c) acc[r][c] += av[r] * bv[c];
        }
        __syncthreads();
    }
    // scatter (seg/h uniform per tile since tiles are 64-aligned)
#pragma unroll
    for (int r = 0; r < 4; ++r) {
        int m = m0 + ty * 4 + r;
        int b = m >> 11, i = m & 2047;
#pragma unroll
        for (int c = 0; c < 4; ++c) {
            int col = n0 + tx * 4 + c;
            float val = acc[r][c];
            int seg = col >> 9;            // 0=q 1=k 2=v
            int cc = col & 511;
            int h = cc >> 6, d = cc & 63;
            if (seg == 0)
                q[((size_t)(b * NH + h) * NN + i) * HD + d] = val;
            else if (seg == 2)
                v[((size_t)(b * NH + h) * NN + i) * HD + d] = val;
            else
                kT[((size_t)(b * NH + h) * HD + d) * NN + i] = val;
        }
    }
}

// ---------------------------------------------------------------------------
// Kernel C: attention. One block = (b, h, 4 query rows). 256 threads.
// scores in LDS [4][2048]; mask from adj stats; softmax; PV.
// ---------------------------------------------------------------------------
#define ROWS 4
__global__ __launch_bounds__(256) void attn_kernel(const float* __restrict__ q,
                                                   const float* __restrict__ kT,
                                                   const float* __restrict__ vv,
                                                   const float* __restrict__ adj,
                                                   const float* __restrict__ rmax,
                                                   const float* __restrict__ rsum,
                                                   float* __restrict__ outh) {
    __shared__ float s[ROWS][NN];
    __shared__ float qs[ROWS][HD];
    __shared__ float red[256];
    __shared__ float part[4][ROWS][HD];
    int t = threadIdx.x;
    int blk = blockIdx.x;
    int i0 = (blk % (NN / ROWS)) * ROWS;
    int h  = (blk / (NN / ROWS)) % NH;
    int b  = blk / ((NN / ROWS) * NH);

    const float* qbase = q + ((size_t)(b * NH + h) * NN + i0) * HD;
    if (t < ROWS * HD) qs[t >> 6][t & 63] = qbase[t];
    __syncthreads();

    // phase 1: dots (q . k) for 4 rows x 2048 cols
    const float* kbase = kT + (size_t)(b * NH + h) * HD * NN;
    float acc[ROWS][8];
#pragma unroll
    for (int r = 0; r < ROWS; ++r)
#pragma unroll
        for (int c = 0; c < 8; ++c) acc[r][c] = 0.f;
    for (int d = 0; d < HD; ++d) {
        const float* kd = kbase + (size_t)d * NN;
        float kvv[8];
#pragma unroll
        for (int c = 0; c < 8; ++c) kvv[c] = kd[t + 256 * c];
#pragma unroll
        for (int r = 0; r < ROWS; ++r) {
            float qv = qs[r][d];
#pragma unroll
            for (int c = 0; c < 8; ++c) acc[r][c] += qv * kvv[c];
        }
    }
    // apply adjacency-softmax mask and scale
#pragma unroll
    for (int r = 0; r < ROWS; ++r) {
        int i = i0 + r;
        const float* arow = adj + ((size_t)b * NN + i) * NN;
        float mx = rmax[b * NN + i];
        float inv = 1.0f / rsum[b * NN + i];
#pragma unroll
        for (int c = 0; c < 8; ++c) {
            int j = t + 256 * c;
            float mask = __expf(arow[j] - mx) * inv;
            s[r][j] = mask * acc[r][c] * SCALE;
        }
    }
    __syncthreads();

    // phase 2: per-row softmax over 2048
    for (int r = 0; r < ROWS; ++r) {
        float mx = -INFINITY;
#pragma unroll
        for (int c = 0; c < 8; ++c) mx = fmaxf(mx, s[r][t + 256 * c]);
        red[t] = mx; __syncthreads();
        for (int st = 128; st > 0; st >>= 1) {
            if (t < st) red[t] = fmaxf(red[t], red[t + st]);
            __syncthreads();
        }
        mx = red[0]; __syncthreads();
        float sm = 0.f;
#pragma unroll
        for (int c = 0; c < 8; ++c) {
            float e = __expf(s[r][t + 256 * c] - mx);
            s[r][t + 256 * c] = e;
            sm += e;
        }
        red[t] = sm; __syncthreads();
        for (int st = 128; st > 0; st >>= 1) {
            if (t < st) red[t] += red[t + st];
            __syncthreads();
        }
        float inv = 1.0f / red[0]; __syncthreads();
#pragma unroll
        for (int c = 0; c < 8; ++c) s[r][t + 256 * c] *= inv;
    }
    __syncthreads();

    // phase 3: out = attn @ v. thread t: d = t&63, j-chunk = t>>6
    int d = t & 63, chunk = t >> 6;
    const float* vbase = vv + (size_t)(b * NH + h) * NN * HD;
    float oacc[ROWS];
#pragma unroll
    for (int r = 0; r < ROWS; ++r) oacc[r] = 0.f;
    for (int j = chunk * 512; j < chunk * 512 + 512; ++j) {
        float vval = vbase[(size_t)j * HD + d];
#pragma unroll
        for (int r = 0; r < ROWS; ++r) oacc[r] += s[r][j] * vval;
    }
#pragma unroll
    for (int r = 0; r < ROWS; ++r) part[chunk][r][d] = oacc[r];
    __syncthreads();
    if (chunk == 0) {
#pragma unroll
        for (int r = 0; r < ROWS; ++r) {
            float o = part[0][r][d] + part[1][r][d] + part[2][r][d] + part[3][r][d];
            outh[((size_t)b * NN + i0 + r) * (NH * HD) + h * HD + d] = o;
        }
    }
}

// ---------------------------------------------------------------------------
// Kernel D: out = outh @ w_out + b_out.  M=4096, K=512, N=512.
// ---------------------------------------------------------------------------
__global__ __launch_bounds__(256) void out_gemm(const float* __restrict__ A,
                                                const float* __restrict__ w,
                                                const float* __restrict__ bias,
                                                float* __restrict__ out) {
    __shared__ __align__(16) float As[16][64];
    __shared__ __align__(16) float Bs[16][64];
    int tx = threadIdx.x & 15, ty = threadIdx.x >> 4;
    int m0 = blockIdx.y * 64;
    int n0 = blockIdx.x * 64;
    float acc[4][4] = {};
    for (int k0 = 0; k0 < 512; k0 += 16) {
        for (int l = threadIdx.x; l < 64 * 16; l += 256) {
            int col = l & 15, row = l >> 4;
            As[col][row] = A[(size_t)(m0 + row) * 512 + k0 + col];
        }
        for (int l = threadIdx.x; l < 16 * 64; l += 256) {
            int col = l & 63, row = l >> 6;
            Bs[row][col] = w[(size_t)(k0 + row) * 512 + n0 + col];
        }
        __syncthreads();
#pragma unroll
        for (int k = 0; k < 16; ++k) {
            float4 a4 = *(const float4*)&As[k][ty * 4];
            float4 b4 = *(const float4*)&Bs[k][tx * 4];
            float av[4] = {a4.x, a4.y, a4.z, a4.w};
            float bv[4] = {b4.x, b4.y, b4.z, b4.w};
#pragma unroll
            for (int r = 0; r < 4; ++r)
#pragma unroll
                for (int c = 0; c < 4; ++c) acc[r][c] += av[r] * bv[c];
        }
        __syncthreads();
    }
#pragma unroll
    for (int r = 0; r < 4; ++r) {
        int m = m0 + ty * 4 + r;
#pragma unroll
        for (int c = 0; c < 4; ++c) {
            int n = n0 + tx * 4 + c;
            out[(size_t)m * 512 + n] = acc[r][c] + bias[n];
        }
    }
}

extern "C" void kernel_launch(void* const* d_in, const int* in_sizes, int n_in,
                              void* d_out, int out_size, void* d_ws, size_t ws_size,
                              hipStream_t stream) {
    const float* x     = (const float*)d_in[0];
    const float* adj   = (const float*)d_in[1];
    const float* w_qkv = (const float*)d_in[2];
    const float* w_out = (const float*)d_in[3];
    const float* b_out = (const float*)d_in[4];
    float* out = (float*)d_out;
    float* ws  = (float*)d_ws;

    float* q    = ws + OFF_Q;
    float* kT   = ws + OFF_KT;
    float* v    = ws + OFF_V;
    float* outh = ws + OFF_OH;
    float* rmax = ws + OFF_RMAX;
    float* rsum = ws + OFF_RSUM;

    adj_stats<<<BB * NN, 256, 0, stream>>>(adj, rmax, rsum);
    qkv_gemm<<<dim3(1536 / 64, (BB * NN) / 64), 256, 0, stream>>>(x, w_qkv, q, kT, v);
    attn_kernel<<<BB * NH * (NN / ROWS), 256, 0, stream>>>(q, kT, v, adj, rmax, rsum, outh);
    out_gemm<<<dim3(512 / 64, (BB * NN) / 64), 256, 0, stream>>>(outh, w_out, b_out, out);
}

// Round 2
// 384.233 us; speedup vs baseline: 1.7622x; 1.7622x over previous
//
#include <hip/hip_runtime.h>
#include <hip/hip_bf16.h>
#include <math.h>

// Problem constants
#define BB 2
#define NN 2048
#define DIM 512
#define NH 8
#define HD 64
#define SCALE 0.125f

typedef __bf16 bf16x8 __attribute__((ext_vector_type(8)));
typedef float floatx4 __attribute__((ext_vector_type(4)));

static inline __device__ floatx4 mfma16(bf16x8 a, bf16x8 b, floatx4 c) {
    return __builtin_amdgcn_mfma_f32_16x16x32_bf16(a, b, c, 0, 0, 0);
}

// ---------------------------------------------------------------------------
// Kernel A: per-row softmax stats of adj  (rmax, rsum) over last axis
// ---------------------------------------------------------------------------
__global__ __launch_bounds__(256) void adj_stats(const float* __restrict__ adj,
                                                 float* __restrict__ rmax,
                                                 float* __restrict__ rsum) {
    int row = blockIdx.x;                 // b*NN + i
    const float* a = adj + (size_t)row * NN;
    int t = threadIdx.x;
    float v[8];
    float mx = -INFINITY;
#pragma unroll
    for (int c = 0; c < 8; ++c) { v[c] = a[t + 256 * c]; mx = fmaxf(mx, v[c]); }
    __shared__ float red[256];
    red[t] = mx; __syncthreads();
    for (int s = 128; s > 0; s >>= 1) {
        if (t < s) red[t] = fmaxf(red[t], red[t + s]);
        __syncthreads();
    }
    mx = red[0]; __syncthreads();
    float sm = 0.f;
#pragma unroll
    for (int c = 0; c < 8; ++c) sm += __expf(v[c] - mx);
    red[t] = sm; __syncthreads();
    for (int s = 128; s > 0; s >>= 1) {
        if (t < s) red[t] += red[t + s];
        __syncthreads();
    }
    if (t == 0) { rmax[row] = mx; rsum[row] = red[0]; }
}

// ---------------------------------------------------------------------------
// Kernel A2: mask = softmax(adj) rows -> bf16
// ---------------------------------------------------------------------------
__global__ __launch_bounds__(256) void mask_kernel(const float* __restrict__ adj,
                                                   const float* __restrict__ rmax,
                                                   const float* __restrict__ rsum,
                                                   __bf16* __restrict__ mask) {
    int row = blockIdx.x;
    const float* a = adj + (size_t)row * NN;
    __bf16* m = mask + (size_t)row * NN;
    int t = threadIdx.x;
    float mx = rmax[row];
    float inv = 1.0f / rsum[row];
#pragma unroll
    for (int c = 0; c < 8; ++c) {
        int j = t + 256 * c;
        m[j] = (__bf16)(__expf(a[j] - mx) * inv);
    }
}

// ---------------------------------------------------------------------------
// Kernel B: qkv = x @ w_qkv, scatter bf16 into q[b,h,n,d], k[b,h,n,d], vT[b,h,d,n]
// ---------------------------------------------------------------------------
__global__ __launch_bounds__(256) void qkv_gemm(const float* __restrict__ x,
                                                const float* __restrict__ w,
                                                __bf16* __restrict__ q,
                                                __bf16* __restrict__ k,
                                                __bf16* __restrict__ vT) {
    __shared__ __align__(16) float As[16][64];   // [k][m]
    __shared__ __align__(16) float Bs[16][64];   // [k][n]
    int tx = threadIdx.x & 15, ty = threadIdx.x >> 4;
    int m0 = blockIdx.y * 64;
    int n0 = blockIdx.x * 64;
    float acc[4][4] = {};
    for (int k0 = 0; k0 < 512; k0 += 16) {
        for (int l = threadIdx.x; l < 64 * 16; l += 256) {
            int col = l & 15, row = l >> 4;
            As[col][row] = x[(size_t)(m0 + row) * 512 + k0 + col];
        }
        for (int l = threadIdx.x; l < 16 * 64; l += 256) {
            int col = l & 63, row = l >> 6;
            Bs[row][col] = w[(size_t)(k0 + row) * 1536 + n0 + col];
        }
        __syncthreads();
#pragma unroll
        for (int kk = 0; kk < 16; ++kk) {
            float4 a4 = *(const float4*)&As[kk][ty * 4];
            float4 b4 = *(const float4*)&Bs[kk][tx * 4];
            float av[4] = {a4.x, a4.y, a4.z, a4.w};
            float bv[4] = {b4.x, b4.y, b4.z, b4.w};
#pragma unroll
            for (int r = 0; r < 4; ++r)
#pragma unroll
                for (int c = 0; c < 4; ++c) acc[r][c] += av[r] * bv[c];
        }
        __syncthreads();
    }
#pragma unroll
    for (int r = 0; r < 4; ++r) {
        int m = m0 + ty * 4 + r;
        int b = m >> 11, i = m & 2047;
#pragma unroll
        for (int c = 0; c < 4; ++c) {
            int col = n0 + tx * 4 + c;
            __bf16 val = (__bf16)acc[r][c];
            int seg = col >> 9;            // 0=q 1=k 2=v
            int cc = col & 511;
            int h = cc >> 6, d = cc & 63;
            size_t bh = (size_t)(b * NH + h);
            if (seg == 0)
                q[(bh * NN + i) * HD + d] = val;
            else if (seg == 1)
                k[(bh * NN + i) * HD + d] = val;
            else
                vT[(bh * HD + d) * NN + i] = val;
        }
    }
}

// ---------------------------------------------------------------------------
// Kernel C: flash attention with MFMA. Block = (b, h, 64 q-rows), 4 waves.
// ---------------------------------------------------------------------------
__global__ __launch_bounds__(256) void flash_attn(const __bf16* __restrict__ qb,
                                                  const __bf16* __restrict__ kb,
                                                  const __bf16* __restrict__ vTb,
                                                  const __bf16* __restrict__ maskb,
                                                  float* __restrict__ outh) {
    // stride 72 bf16 (144 B): b128 reads land <=2-way on banks (free per m136)
    __shared__ __bf16 Ks[64][72];   // rows j-local, cols d
    __shared__ __bf16 Vs[64][72];   // rows d,       cols j-local
    __shared__ __bf16 Ps[64][72];   // rows i-local, cols j-local
    __shared__ __bf16 Ms[64][72];   // rows i-local, cols j-local

    const int t = threadIdx.x;
    const int lane = t & 63;
    const int w = t >> 6;           // wave 0..3 -> i-strip
    const int n16 = lane & 15;
    const int quad = lane >> 4;

    const int blk = blockIdx.x;
    const int it = blk & 31;
    const int h = (blk >> 5) & 7;
    const int b = blk >> 8;
    const int i0 = it * 64;
    const int bh = b * NH + h;

    // Q A-frags (rows i0+16w+n16, k = ks*32 + quad*8 + [0,8))
    bf16x8 qfrag[2];
    {
        const __bf16* qrow = qb + ((size_t)bh * NN + i0 + w * 16 + n16) * HD;
        qfrag[0] = *(const bf16x8*)(qrow + quad * 8);
        qfrag[1] = *(const bf16x8*)(qrow + 32 + quad * 8);
    }

    floatx4 O[4];
#pragma unroll
    for (int dt = 0; dt < 4; ++dt) O[dt] = (floatx4){0.f, 0.f, 0.f, 0.f};
    float mrow[4], lrow[4];
#pragma unroll
    for (int r = 0; r < 4; ++r) { mrow[r] = -INFINITY; lrow[r] = 0.f; }

    const int srow = t >> 3, sseg = t & 7;        // staging: chunk c = t, t+256
    const int srow2 = (t + 256) >> 3, sseg2 = (t + 256) & 7;

    for (int j0 = 0; j0 < NN; j0 += 64) {
        __syncthreads();   // previous iteration's LDS reads done
        // ---- stage K, vT, M tiles ----
        {
            const __bf16* kg = kb + ((size_t)bh * NN + j0) * HD;
            const __bf16* vg = vTb + (size_t)bh * HD * NN + j0;
            const __bf16* mg = maskb + ((size_t)b * NN + i0) * NN + j0;
            float4 k1 = *(const float4*)(kg + (size_t)srow * HD + sseg * 8);
            float4 k2 = *(const float4*)(kg + (size_t)srow2 * HD + sseg2 * 8);
            float4 v1 = *(const float4*)(vg + (size_t)srow * NN + sseg * 8);
            float4 v2 = *(const float4*)(vg + (size_t)srow2 * NN + sseg2 * 8);
            float4 m1 = *(const float4*)(mg + (size_t)srow * NN + sseg * 8);
            float4 m2 = *(const float4*)(mg + (size_t)srow2 * NN + sseg2 * 8);
            *(float4*)(&Ks[srow][sseg * 8]) = k1;
            *(float4*)(&Ks[srow2][sseg2 * 8]) = k2;
            *(float4*)(&Vs[srow][sseg * 8]) = v1;
            *(float4*)(&Vs[srow2][sseg2 * 8]) = v2;
            *(float4*)(&Ms[srow][sseg * 8]) = m1;
            *(float4*)(&Ms[srow2][sseg2 * 8]) = m2;
        }
        __syncthreads();

        // ---- QK^T: S strip 16 x 64 ----
        floatx4 S[4];
#pragma unroll
        for (int jt = 0; jt < 4; ++jt) {
            floatx4 acc = (floatx4){0.f, 0.f, 0.f, 0.f};
            bf16x8 kf0 = *(const bf16x8*)(&Ks[jt * 16 + n16][quad * 8]);
            bf16x8 kf1 = *(const bf16x8*)(&Ks[jt * 16 + n16][32 + quad * 8]);
            acc = mfma16(qfrag[0], kf0, acc);
            acc = mfma16(qfrag[1], kf1, acc);
            S[jt] = acc;
        }

        // ---- mask + online softmax ----
        float p[4][4];
        float tmax[4] = {-INFINITY, -INFINITY, -INFINITY, -INFINITY};
#pragma unroll
        for (int jt = 0; jt < 4; ++jt) {
#pragma unroll
            for (int r = 0; r < 4; ++r) {
                int il = w * 16 + quad * 4 + r;
                int jl = jt * 16 + n16;
                float mval = (float)Ms[il][jl];
                float s = S[jt][r] * SCALE * mval;
                p[jt][r] = s;
                tmax[r] = fmaxf(tmax[r], s);
            }
        }
#pragma unroll
        for (int r = 0; r < 4; ++r) {
            float v = tmax[r];
            v = fmaxf(v, __shfl_xor(v, 1));
            v = fmaxf(v, __shfl_xor(v, 2));
            v = fmaxf(v, __shfl_xor(v, 4));
            v = fmaxf(v, __shfl_xor(v, 8));
            float mnew = fmaxf(mrow[r], v);
            tmax[r] = __expf(mrow[r] - mnew);   // alpha
            mrow[r] = mnew;
        }
        float tsum[4] = {0.f, 0.f, 0.f, 0.f};
#pragma unroll
        for (int jt = 0; jt < 4; ++jt)
#pragma unroll
            for (int r = 0; r < 4; ++r) {
                float e = __expf(p[jt][r] - mrow[r]);
                p[jt][r] = e;
                tsum[r] += e;
            }
#pragma unroll
        for (int r = 0; r < 4; ++r) {
            float v = tsum[r];
            v += __shfl_xor(v, 1);
            v += __shfl_xor(v, 2);
            v += __shfl_xor(v, 4);
            v += __shfl_xor(v, 8);
            lrow[r] = lrow[r] * tmax[r] + v;
        }
#pragma unroll
        for (int dt = 0; dt < 4; ++dt)
#pragma unroll
            for (int r = 0; r < 4; ++r) O[dt][r] *= tmax[r];
        // write P (bf16) to LDS
#pragma unroll
        for (int jt = 0; jt < 4; ++jt)
#pragma unroll
            for (int r = 0; r < 4; ++r) {
                int il = w * 16 + quad * 4 + r;
                Ps[il][jt * 16 + n16] = (__bf16)p[jt][r];
            }
        __syncthreads();

        // ---- PV: O strip 16 x 64 += P(16x64) @ V(64x64) ----
        bf16x8 pf0 = *(const bf16x8*)(&Ps[w * 16 + n16][quad * 8]);
        bf16x8 pf1 = *(const bf16x8*)(&Ps[w * 16 + n16][32 + quad * 8]);
#pragma unroll
        for (int dt = 0; dt < 4; ++dt) {
            bf16x8 vf0 = *(const bf16x8*)(&Vs[dt * 16 + n16][quad * 8]);
            bf16x8 vf1 = *(const bf16x8*)(&Vs[dt * 16 + n16][32 + quad * 8]);
            O[dt] = mfma16(pf0, vf0, O[dt]);
            O[dt] = mfma16(pf1, vf1, O[dt]);
        }
    }

    // ---- epilogue ----
#pragma unroll
    for (int dt = 0; dt < 4; ++dt)
#pragma unroll
        for (int r = 0; r < 4; ++r) {
            int i = i0 + w * 16 + quad * 4 + r;
            int d = dt * 16 + n16;
            outh[((size_t)b * NN + i) * (NH * HD) + h * HD + d] = O[dt][r] / lrow[r];
        }
}

// ---------------------------------------------------------------------------
// Kernel D: out = outh @ w_out + b_out.  M=4096, K=512, N=512. (fp32)
// ---------------------------------------------------------------------------
__global__ __launch_bounds__(256) void out_gemm(const float* __restrict__ A,
                                                const float* __restrict__ w,
                                                const float* __restrict__ bias,
                                                float* __restrict__ out) {
    __shared__ __align__(16) float As[16][64];
    __shared__ __align__(16) float Bs[16][64];
    int tx = threadIdx.x & 15, ty = threadIdx.x >> 4;
    int m0 = blockIdx.y * 64;
    int n0 = blockIdx.x * 64;
    float acc[4][4] = {};
    for (int k0 = 0; k0 < 512; k0 += 16) {
        for (int l = threadIdx.x; l < 64 * 16; l += 256) {
            int col = l & 15, row = l >> 4;
            As[col][row] = A[(size_t)(m0 + row) * 512 + k0 + col];
        }
        for (int l = threadIdx.x; l < 16 * 64; l += 256) {
            int col = l & 63, row = l >> 6;
            Bs[row][col] = w[(size_t)(k0 + row) * 512 + n0 + col];
        }
        __syncthreads();
#pragma unroll
        for (int kk = 0; kk < 16; ++kk) {
            float4 a4 = *(const float4*)&As[kk][ty * 4];
            float4 b4 = *(const float4*)&Bs[kk][tx * 4];
            float av[4] = {a4.x, a4.y, a4.z, a4.w};
            float bv[4] = {b4.x, b4.y, b4.z, b4.w};
#pragma unroll
            for (int r = 0; r < 4; ++r)
#pragma unroll
                for (int c = 0; c < 4; ++c) acc[r][c] += av[r] * bv[c];
        }
        __syncthreads();
    }
#pragma unroll
    for (int r = 0; r < 4; ++r) {
        int m = m0 + ty * 4 + r;
#pragma unroll
        for (int c = 0; c < 4; ++c) {
            int n = n0 + tx * 4 + c;
            out[(size_t)m * 512 + n] = acc[r][c] + bias[n];
        }
    }
}

extern "C" void kernel_launch(void* const* d_in, const int* in_sizes, int n_in,
                              void* d_out, int out_size, void* d_ws, size_t ws_size,
                              hipStream_t stream) {
    const float* x     = (const float*)d_in[0];
    const float* adj   = (const float*)d_in[1];
    const float* w_qkv = (const float*)d_in[2];
    const float* w_out = (const float*)d_in[3];
    const float* b_out = (const float*)d_in[4];
    float* out = (float*)d_out;
    char* wsb = (char*)d_ws;

    // byte offsets
    __bf16* q    = (__bf16*)(wsb + 0);                     //  4 MiB
    __bf16* k    = (__bf16*)(wsb + (4u << 20));            //  4 MiB
    __bf16* vT   = (__bf16*)(wsb + (8u << 20));            //  4 MiB
    __bf16* mask = (__bf16*)(wsb + (12u << 20));           // 16 MiB
    float*  outh = (float*) (wsb + (28u << 20));           //  8 MiB
    float*  rmax = (float*) (wsb + (36u << 20));
    float*  rsum = (float*) (wsb + (36u << 20) + 16384);

    adj_stats<<<BB * NN, 256, 0, stream>>>(adj, rmax, rsum);
    mask_kernel<<<BB * NN, 256, 0, stream>>>(adj, rmax, rsum, mask);
    qkv_gemm<<<dim3(1536 / 64, (BB * NN) / 64), 256, 0, stream>>>(x, w_qkv, q, k, vT);
    flash_attn<<<BB * NH * (NN / 64), 256, 0, stream>>>(q, k, vT, mask, outh);
    out_gemm<<<dim3(512 / 64, (BB * NN) / 64), 256, 0, stream>>>(outh, w_out, b_out, out);
}

// Round 3
// 220.706 us; speedup vs baseline: 3.0678x; 1.7409x over previous
//
#include <hip/hip_runtime.h>
#include <hip/hip_bf16.h>
#include <math.h>

// Problem constants
#define BB 2
#define NN 2048
#define DIM 512
#define NH 8
#define HD 64
#define SCALE 0.125f

typedef __bf16 bf16x8 __attribute__((ext_vector_type(8)));
typedef float floatx4 __attribute__((ext_vector_type(4)));

static inline __device__ floatx4 mfma16(bf16x8 a, bf16x8 b, floatx4 c) {
    return __builtin_amdgcn_mfma_f32_16x16x32_bf16(a, b, c, 0, 0, 0);
}

static inline __device__ bf16x8 cvt8(float4 a, float4 b) {
    bf16x8 r;
    r[0] = (__bf16)a.x; r[1] = (__bf16)a.y; r[2] = (__bf16)a.z; r[3] = (__bf16)a.w;
    r[4] = (__bf16)b.x; r[5] = (__bf16)b.y; r[6] = (__bf16)b.z; r[7] = (__bf16)b.w;
    return r;
}

// ---------------------------------------------------------------------------
// Kernel A: fused softmax(adj) rows -> bf16 mask
// ---------------------------------------------------------------------------
__global__ __launch_bounds__(256) void adj_softmax(const float* __restrict__ adj,
                                                   __bf16* __restrict__ mask) {
    int row = blockIdx.x;                 // b*NN + i
    const float* a = adj + (size_t)row * NN;
    __bf16* m = mask + (size_t)row * NN;
    int t = threadIdx.x;
    float v[8];
    float mx = -INFINITY;
#pragma unroll
    for (int c = 0; c < 8; ++c) { v[c] = a[t + 256 * c]; mx = fmaxf(mx, v[c]); }
    __shared__ float red[256];
    red[t] = mx; __syncthreads();
    for (int s = 128; s > 0; s >>= 1) {
        if (t < s) red[t] = fmaxf(red[t], red[t + s]);
        __syncthreads();
    }
    mx = red[0]; __syncthreads();
    float sm = 0.f;
    float e[8];
#pragma unroll
    for (int c = 0; c < 8; ++c) { e[c] = __expf(v[c] - mx); sm += e[c]; }
    red[t] = sm; __syncthreads();
    for (int s = 128; s > 0; s >>= 1) {
        if (t < s) red[t] += red[t + s];
        __syncthreads();
    }
    float inv = 1.0f / red[0];
#pragma unroll
    for (int c = 0; c < 8; ++c) m[t + 256 * c] = (__bf16)(e[c] * inv);
}

// ---------------------------------------------------------------------------
// Kernel B: transpose + cast weight  w[K][N] fp32 -> wT[N][K] bf16
// grid (N/32, K/32), 256 threads
// ---------------------------------------------------------------------------
__global__ __launch_bounds__(256) void tcast_w(const float* __restrict__ w,
                                               __bf16* __restrict__ wT,
                                               int K, int N) {
    __shared__ float tile[32][33];
    int n0 = blockIdx.x * 32, k0 = blockIdx.y * 32;
    int c = threadIdx.x & 31, r = threadIdx.x >> 5;   // r in 0..7
#pragma unroll
    for (int p = 0; p < 4; ++p)
        tile[r + p * 8][c] = w[(size_t)(k0 + r + p * 8) * N + n0 + c];
    __syncthreads();
#pragma unroll
    for (int p = 0; p < 4; ++p)
        wT[(size_t)(n0 + r + p * 8) * K + k0 + c] = (__bf16)tile[c][r + p * 8];
}

// ---------------------------------------------------------------------------
// Kernel C: qkv = x @ w_qkv via MFMA. 128x128 tile, BK=32, 4 waves (2x2).
// A: fp32 x cast in-flight. B: pre-transposed bf16 wT [1536][512].
// Scatter bf16 into q[b,h,n,d], k[b,h,n,d], vT[b,h,d,n].
// ---------------------------------------------------------------------------
__global__ __launch_bounds__(256) void qkv_mfma(const float* __restrict__ x,
                                                const __bf16* __restrict__ wT,
                                                __bf16* __restrict__ q,
                                                __bf16* __restrict__ kk,
                                                __bf16* __restrict__ vT) {
    __shared__ __bf16 As[128 * 40];   // [row][k], stride 40 (2-way banks, free)
    __shared__ __bf16 Bs[128 * 40];
    const int t = threadIdx.x;
    const int lane = t & 63, w = t >> 6;
    const int n16 = lane & 15, quad = lane >> 4;
    const int wm = w >> 1, wn = w & 1;
    const int m0 = blockIdx.y * 128, n0 = blockIdx.x * 128;
    const int r1 = t >> 2, seg = t & 3;     // staging rows r1, r1+64

    floatx4 acc[4][4];
#pragma unroll
    for (int mt = 0; mt < 4; ++mt)
#pragma unroll
        for (int nt = 0; nt < 4; ++nt) acc[mt][nt] = (floatx4){0.f, 0.f, 0.f, 0.f};

    for (int k0 = 0; k0 < 512; k0 += 32) {
        const float* xs1 = x + (size_t)(m0 + r1) * 512 + k0 + seg * 8;
        const float* xs2 = xs1 + (size_t)64 * 512;
        float4 fa1 = *(const float4*)xs1, fa2 = *(const float4*)(xs1 + 4);
        float4 fb1 = *(const float4*)xs2, fb2 = *(const float4*)(xs2 + 4);
        bf16x8 a1 = cvt8(fa1, fa2), a2 = cvt8(fb1, fb2);
        bf16x8 w1 = *(const bf16x8*)(wT + (size_t)(n0 + r1) * 512 + k0 + seg * 8);
        bf16x8 w2 = *(const bf16x8*)(wT + (size_t)(n0 + r1 + 64) * 512 + k0 + seg * 8);
        __syncthreads();
        *(bf16x8*)(As + r1 * 40 + seg * 8) = a1;
        *(bf16x8*)(As + (r1 + 64) * 40 + seg * 8) = a2;
        *(bf16x8*)(Bs + r1 * 40 + seg * 8) = w1;
        *(bf16x8*)(Bs + (r1 + 64) * 40 + seg * 8) = w2;
        __syncthreads();
        bf16x8 af[4], bf[4];
#pragma unroll
        for (int mt = 0; mt < 4; ++mt)
            af[mt] = *(const bf16x8*)(As + (wm * 64 + mt * 16 + n16) * 40 + quad * 8);
#pragma unroll
        for (int nt = 0; nt < 4; ++nt)
            bf[nt] = *(const bf16x8*)(Bs + (wn * 64 + nt * 16 + n16) * 40 + quad * 8);
#pragma unroll
        for (int mt = 0; mt < 4; ++mt)
#pragma unroll
            for (int nt = 0; nt < 4; ++nt)
                acc[mt][nt] = mfma16(af[mt], bf[nt], acc[mt][nt]);
    }

    // scatter epilogue; seg uniform per block (128-col tile inside one 512 segment)
#pragma unroll
    for (int mt = 0; mt < 4; ++mt)
#pragma unroll
        for (int nt = 0; nt < 4; ++nt)
#pragma unroll
            for (int r = 0; r < 4; ++r) {
                int m = m0 + wm * 64 + mt * 16 + quad * 4 + r;
                int n = n0 + wn * 64 + nt * 16 + n16;
                int b = m >> 11, i = m & 2047;
                int sg = n >> 9, cc = n & 511;
                int h = cc >> 6, d = cc & 63;
                size_t bh = (size_t)(b * NH + h);
                __bf16 val = (__bf16)acc[mt][nt][r];
                if (sg == 0)      q[(bh * NN + i) * HD + d] = val;
                else if (sg == 1) kk[(bh * NN + i) * HD + d] = val;
                else              vT[(bh * HD + d) * NN + i] = val;
            }
}

// ---------------------------------------------------------------------------
// Kernel D: flash attention with MFMA. Block = (b, h, 64 q-rows), 4 waves.
// Writes bf16 ohb [b, n, h*d].
// ---------------------------------------------------------------------------
__global__ __launch_bounds__(256) void flash_attn(const __bf16* __restrict__ qb,
                                                  const __bf16* __restrict__ kb,
                                                  const __bf16* __restrict__ vTb,
                                                  const __bf16* __restrict__ maskb,
                                                  __bf16* __restrict__ ohb) {
    __shared__ __bf16 Ks[64][72];   // rows j-local, cols d
    __shared__ __bf16 Vs[64][72];   // rows d,       cols j-local
    __shared__ __bf16 Ps[64][72];   // rows i-local, cols j-local
    __shared__ __bf16 Ms[64][72];   // rows i-local, cols j-local

    const int t = threadIdx.x;
    const int lane = t & 63;
    const int w = t >> 6;           // wave 0..3 -> i-strip
    const int n16 = lane & 15;
    const int quad = lane >> 4;

    const int blk = blockIdx.x;
    const int it = blk & 31;
    const int h = (blk >> 5) & 7;
    const int b = blk >> 8;
    const int i0 = it * 64;
    const int bh = b * NH + h;

    bf16x8 qfrag[2];
    {
        const __bf16* qrow = qb + ((size_t)bh * NN + i0 + w * 16 + n16) * HD;
        qfrag[0] = *(const bf16x8*)(qrow + quad * 8);
        qfrag[1] = *(const bf16x8*)(qrow + 32 + quad * 8);
    }

    floatx4 O[4];
#pragma unroll
    for (int dt = 0; dt < 4; ++dt) O[dt] = (floatx4){0.f, 0.f, 0.f, 0.f};
    float mrow[4], lrow[4];
#pragma unroll
    for (int r = 0; r < 4; ++r) { mrow[r] = -INFINITY; lrow[r] = 0.f; }

    const int srow = t >> 3, sseg = t & 7;
    const int srow2 = (t + 256) >> 3, sseg2 = (t + 256) & 7;

    for (int j0 = 0; j0 < NN; j0 += 64) {
        __syncthreads();
        {
            const __bf16* kg = kb + ((size_t)bh * NN + j0) * HD;
            const __bf16* vg = vTb + (size_t)bh * HD * NN + j0;
            const __bf16* mg = maskb + ((size_t)b * NN + i0) * NN + j0;
            float4 k1 = *(const float4*)(kg + (size_t)srow * HD + sseg * 8);
            float4 k2 = *(const float4*)(kg + (size_t)srow2 * HD + sseg2 * 8);
            float4 v1 = *(const float4*)(vg + (size_t)srow * NN + sseg * 8);
            float4 v2 = *(const float4*)(vg + (size_t)srow2 * NN + sseg2 * 8);
            float4 m1 = *(const float4*)(mg + (size_t)srow * NN + sseg * 8);
            float4 m2 = *(const float4*)(mg + (size_t)srow2 * NN + sseg2 * 8);
            *(float4*)(&Ks[srow][sseg * 8]) = k1;
            *(float4*)(&Ks[srow2][sseg2 * 8]) = k2;
            *(float4*)(&Vs[srow][sseg * 8]) = v1;
            *(float4*)(&Vs[srow2][sseg2 * 8]) = v2;
            *(float4*)(&Ms[srow][sseg * 8]) = m1;
            *(float4*)(&Ms[srow2][sseg2 * 8]) = m2;
        }
        __syncthreads();

        floatx4 S[4];
#pragma unroll
        for (int jt = 0; jt < 4; ++jt) {
            floatx4 acc = (floatx4){0.f, 0.f, 0.f, 0.f};
            bf16x8 kf0 = *(const bf16x8*)(&Ks[jt * 16 + n16][quad * 8]);
            bf16x8 kf1 = *(const bf16x8*)(&Ks[jt * 16 + n16][32 + quad * 8]);
            acc = mfma16(qfrag[0], kf0, acc);
            acc = mfma16(qfrag[1], kf1, acc);
            S[jt] = acc;
        }

        float p[4][4];
        float tmax[4] = {-INFINITY, -INFINITY, -INFINITY, -INFINITY};
#pragma unroll
        for (int jt = 0; jt < 4; ++jt) {
#pragma unroll
            for (int r = 0; r < 4; ++r) {
                int il = w * 16 + quad * 4 + r;
                int jl = jt * 16 + n16;
                float mval = (float)Ms[il][jl];
                float s = S[jt][r] * SCALE * mval;
                p[jt][r] = s;
                tmax[r] = fmaxf(tmax[r], s);
            }
        }
#pragma unroll
        for (int r = 0; r < 4; ++r) {
            float v = tmax[r];
            v = fmaxf(v, __shfl_xor(v, 1));
            v = fmaxf(v, __shfl_xor(v, 2));
            v = fmaxf(v, __shfl_xor(v, 4));
            v = fmaxf(v, __shfl_xor(v, 8));
            float mnew = fmaxf(mrow[r], v);
            tmax[r] = __expf(mrow[r] - mnew);   // alpha
            mrow[r] = mnew;
        }
        float tsum[4] = {0.f, 0.f, 0.f, 0.f};
#pragma unroll
        for (int jt = 0; jt < 4; ++jt)
#pragma unroll
            for (int r = 0; r < 4; ++r) {
                float e = __expf(p[jt][r] - mrow[r]);
                p[jt][r] = e;
                tsum[r] += e;
            }
#pragma unroll
        for (int r = 0; r < 4; ++r) {
            float v = tsum[r];
            v += __shfl_xor(v, 1);
            v += __shfl_xor(v, 2);
            v += __shfl_xor(v, 4);
            v += __shfl_xor(v, 8);
            lrow[r] = lrow[r] * tmax[r] + v;
        }
#pragma unroll
        for (int dt = 0; dt < 4; ++dt)
#pragma unroll
            for (int r = 0; r < 4; ++r) O[dt][r] *= tmax[r];
#pragma unroll
        for (int jt = 0; jt < 4; ++jt)
#pragma unroll
            for (int r = 0; r < 4; ++r) {
                int il = w * 16 + quad * 4 + r;
                Ps[il][jt * 16 + n16] = (__bf16)p[jt][r];
            }
        __syncthreads();

        bf16x8 pf0 = *(const bf16x8*)(&Ps[w * 16 + n16][quad * 8]);
        bf16x8 pf1 = *(const bf16x8*)(&Ps[w * 16 + n16][32 + quad * 8]);
#pragma unroll
        for (int dt = 0; dt < 4; ++dt) {
            bf16x8 vf0 = *(const bf16x8*)(&Vs[dt * 16 + n16][quad * 8]);
            bf16x8 vf1 = *(const bf16x8*)(&Vs[dt * 16 + n16][32 + quad * 8]);
            O[dt] = mfma16(pf0, vf0, O[dt]);
            O[dt] = mfma16(pf1, vf1, O[dt]);
        }
    }

#pragma unroll
    for (int dt = 0; dt < 4; ++dt)
#pragma unroll
        for (int r = 0; r < 4; ++r) {
            int i = i0 + w * 16 + quad * 4 + r;
            int d = dt * 16 + n16;
            ohb[((size_t)b * NN + i) * (NH * HD) + h * HD + d] =
                (__bf16)(O[dt][r] / lrow[r]);
        }
}

// ---------------------------------------------------------------------------
// Kernel E: out = ohb @ w_out + b_out via MFMA. BM=64, BN=128 -> 256 blocks.
// ---------------------------------------------------------------------------
__global__ __launch_bounds__(256) void out_mfma(const __bf16* __restrict__ A,
                                                const __bf16* __restrict__ wT,
                                                const float* __restrict__ bias,
                                                float* __restrict__ out) {
    __shared__ __bf16 As[64 * 40];
    __shared__ __bf16 Bs[128 * 40];
    const int t = threadIdx.x;
    const int lane = t & 63, w = t >> 6;
    const int n16 = lane & 15, quad = lane >> 4;
    const int wm = w >> 1, wn = w & 1;     // wave: 32 rows x 64 cols
    const int m0 = blockIdx.y * 64, n0 = blockIdx.x * 128;
    const int ra = t >> 2, seg = t & 3;    // A: 64 rows (ra<64 uses t<256: ra in 0..63)
    const int rb = t >> 2;                 // B rows rb, rb+64

    floatx4 acc[2][4];
#pragma unroll
    for (int mt = 0; mt < 2; ++mt)
#pragma unroll
        for (int nt = 0; nt < 4; ++nt) acc[mt][nt] = (floatx4){0.f, 0.f, 0.f, 0.f};

    for (int k0 = 0; k0 < 512; k0 += 32) {
        bf16x8 a1 = *(const bf16x8*)(A + (size_t)(m0 + ra) * 512 + k0 + seg * 8);
        bf16x8 w1 = *(const bf16x8*)(wT + (size_t)(n0 + rb) * 512 + k0 + seg * 8);
        bf16x8 w2 = *(const bf16x8*)(wT + (size_t)(n0 + rb + 64) * 512 + k0 + seg * 8);
        __syncthreads();
        *(bf16x8*)(As + ra * 40 + seg * 8) = a1;
        *(bf16x8*)(Bs + rb * 40 + seg * 8) = w1;
        *(bf16x8*)(Bs + (rb + 64) * 40 + seg * 8) = w2;
        __syncthreads();
        bf16x8 af[2], bf[4];
#pragma unroll
        for (int mt = 0; mt < 2; ++mt)
            af[mt] = *(const bf16x8*)(As + (wm * 32 + mt * 16 + n16) * 40 + quad * 8);
#pragma unroll
        for (int nt = 0; nt < 4; ++nt)
            bf[nt] = *(const bf16x8*)(Bs + (wn * 64 + nt * 16 + n16) * 40 + quad * 8);
#pragma unroll
        for (int mt = 0; mt < 2; ++mt)
#pragma unroll
            for (int nt = 0; nt < 4; ++nt)
                acc[mt][nt] = mfma16(af[mt], bf[nt], acc[mt][nt]);
    }

#pragma unroll
    for (int mt = 0; mt < 2; ++mt)
#pragma unroll
        for (int nt = 0; nt < 4; ++nt)
#pragma unroll
            for (int r = 0; r < 4; ++r) {
                int m = m0 + wm * 32 + mt * 16 + quad * 4 + r;
                int n = n0 + wn * 64 + nt * 16 + n16;
                out[(size_t)m * 512 + n] = acc[mt][nt][r] + bias[n];
            }
}

extern "C" void kernel_launch(void* const* d_in, const int* in_sizes, int n_in,
                              void* d_out, int out_size, void* d_ws, size_t ws_size,
                              hipStream_t stream) {
    const float* x     = (const float*)d_in[0];
    const float* adj   = (const float*)d_in[1];
    const float* w_qkv = (const float*)d_in[2];
    const float* w_out = (const float*)d_in[3];
    const float* b_out = (const float*)d_in[4];
    float* out = (float*)d_out;
    char* wsb = (char*)d_ws;

    // workspace byte layout (total 34 MiB)
    __bf16* wqkvT = (__bf16*)(wsb + 0);                 // 1536*512*2 = 1.5 MiB
    __bf16* woutT = (__bf16*)(wsb + (3u << 19));        // 512*512*2  = 0.5 MiB  (@1.5M)
    __bf16* q     = (__bf16*)(wsb + (2u << 20));        // 4 MiB
    __bf16* k     = (__bf16*)(wsb + (6u << 20));        // 4 MiB
    __bf16* vT    = (__bf16*)(wsb + (10u << 20));       // 4 MiB
    __bf16* mask  = (__bf16*)(wsb + (14u << 20));       // 16 MiB
    __bf16* ohb   = (__bf16*)(wsb + (30u << 20));       // 4 MiB

    adj_softmax<<<BB * NN, 256, 0, stream>>>(adj, mask);
    tcast_w<<<dim3(1536 / 32, 512 / 32), 256, 0, stream>>>(w_qkv, wqkvT, 512, 1536);
    tcast_w<<<dim3(512 / 32, 512 / 32), 256, 0, stream>>>(w_out, woutT, 512, 512);
    qkv_mfma<<<dim3(1536 / 128, 4096 / 128), 256, 0, stream>>>(x, wqkvT, q, k, vT);
    flash_attn<<<BB * NH * (NN / 64), 256, 0, stream>>>(q, k, vT, mask, ohb);
    out_mfma<<<dim3(512 / 128, 4096 / 64), 256, 0, stream>>>(ohb, woutT, b_out, out);
}

// Round 4
// 181.752 us; speedup vs baseline: 3.7253x; 1.2143x over previous
//
#include <hip/hip_runtime.h>
#include <hip/hip_bf16.h>
#include <math.h>

// Problem constants
#define BB 2
#define NN 2048
#define DIM 512
#define NH 8
#define HD 64
#define SCALE 0.125f

typedef __bf16 bf16x8 __attribute__((ext_vector_type(8)));
typedef __bf16 bf16x4 __attribute__((ext_vector_type(4)));
typedef float floatx4 __attribute__((ext_vector_type(4)));

static inline __device__ floatx4 mfma16(bf16x8 a, bf16x8 b, floatx4 c) {
    return __builtin_amdgcn_mfma_f32_16x16x32_bf16(a, b, c, 0, 0, 0);
}

static inline __device__ bf16x8 cvt8(float4 a, float4 b) {
    bf16x8 r;
    r[0] = (__bf16)a.x; r[1] = (__bf16)a.y; r[2] = (__bf16)a.z; r[3] = (__bf16)a.w;
    r[4] = (__bf16)b.x; r[5] = (__bf16)b.y; r[6] = (__bf16)b.z; r[7] = (__bf16)b.w;
    return r;
}

static inline __device__ float bf2f(unsigned short u) {
    return __uint_as_float(((unsigned)u) << 16);
}

// ---------------------------------------------------------------------------
// Kernel A: fused softmax(adj) rows -> bf16 mask
// ---------------------------------------------------------------------------
__global__ __launch_bounds__(256) void adj_softmax(const float* __restrict__ adj,
                                                   __bf16* __restrict__ mask) {
    int row = blockIdx.x;                 // b*NN + i
    const float* a = adj + (size_t)row * NN;
    __bf16* m = mask + (size_t)row * NN;
    int t = threadIdx.x;
    float v[8];
    float mx = -INFINITY;
#pragma unroll
    for (int c = 0; c < 8; ++c) { v[c] = a[t + 256 * c]; mx = fmaxf(mx, v[c]); }
    __shared__ float red[256];
    red[t] = mx; __syncthreads();
    for (int s = 128; s > 0; s >>= 1) {
        if (t < s) red[t] = fmaxf(red[t], red[t + s]);
        __syncthreads();
    }
    mx = red[0]; __syncthreads();
    float sm = 0.f;
    float e[8];
#pragma unroll
    for (int c = 0; c < 8; ++c) { e[c] = __expf(v[c] - mx); sm += e[c]; }
    red[t] = sm; __syncthreads();
    for (int s = 128; s > 0; s >>= 1) {
        if (t < s) red[t] += red[t + s];
        __syncthreads();
    }
    float inv = 1.0f / red[0];
#pragma unroll
    for (int c = 0; c < 8; ++c) m[t + 256 * c] = (__bf16)(e[c] * inv);
}

// ---------------------------------------------------------------------------
// Kernel B: transpose + cast weight  w[K][N] fp32 -> wT[N][K] bf16
// ---------------------------------------------------------------------------
__global__ __launch_bounds__(256) void tcast_w(const float* __restrict__ w,
                                               __bf16* __restrict__ wT,
                                               int K, int N) {
    __shared__ float tile[32][33];
    int n0 = blockIdx.x * 32, k0 = blockIdx.y * 32;
    int c = threadIdx.x & 31, r = threadIdx.x >> 5;   // r in 0..7
#pragma unroll
    for (int p = 0; p < 4; ++p)
        tile[r + p * 8][c] = w[(size_t)(k0 + r + p * 8) * N + n0 + c];
    __syncthreads();
#pragma unroll
    for (int p = 0; p < 4; ++p)
        wT[(size_t)(n0 + r + p * 8) * K + k0 + c] = (__bf16)tile[c][r + p * 8];
}

// ---------------------------------------------------------------------------
// Kernel C: qkv = x @ w_qkv via MFMA. 128x128 tile, BK=32, 4 waves (2x2).
// q gets SCALE folded in (exact: 0.125 = 2^-3).
// ---------------------------------------------------------------------------
__global__ __launch_bounds__(256) void qkv_mfma(const float* __restrict__ x,
                                                const __bf16* __restrict__ wT,
                                                __bf16* __restrict__ q,
                                                __bf16* __restrict__ kk,
                                                __bf16* __restrict__ vT) {
    __shared__ __bf16 As[128 * 40];   // [row][k], stride 40
    __shared__ __bf16 Bs[128 * 40];
    const int t = threadIdx.x;
    const int lane = t & 63, w = t >> 6;
    const int n16 = lane & 15, quad = lane >> 4;
    const int wm = w >> 1, wn = w & 1;
    const int m0 = blockIdx.y * 128, n0 = blockIdx.x * 128;
    const int r1 = t >> 2, seg = t & 3;

    floatx4 acc[4][4];
#pragma unroll
    for (int mt = 0; mt < 4; ++mt)
#pragma unroll
        for (int nt = 0; nt < 4; ++nt) acc[mt][nt] = (floatx4){0.f, 0.f, 0.f, 0.f};

    for (int k0 = 0; k0 < 512; k0 += 32) {
        const float* xs1 = x + (size_t)(m0 + r1) * 512 + k0 + seg * 8;
        const float* xs2 = xs1 + (size_t)64 * 512;
        float4 fa1 = *(const float4*)xs1, fa2 = *(const float4*)(xs1 + 4);
        float4 fb1 = *(const float4*)xs2, fb2 = *(const float4*)(xs2 + 4);
        bf16x8 a1 = cvt8(fa1, fa2), a2 = cvt8(fb1, fb2);
        bf16x8 w1 = *(const bf16x8*)(wT + (size_t)(n0 + r1) * 512 + k0 + seg * 8);
        bf16x8 w2 = *(const bf16x8*)(wT + (size_t)(n0 + r1 + 64) * 512 + k0 + seg * 8);
        __syncthreads();
        *(bf16x8*)(As + r1 * 40 + seg * 8) = a1;
        *(bf16x8*)(As + (r1 + 64) * 40 + seg * 8) = a2;
        *(bf16x8*)(Bs + r1 * 40 + seg * 8) = w1;
        *(bf16x8*)(Bs + (r1 + 64) * 40 + seg * 8) = w2;
        __syncthreads();
        bf16x8 af[4], bf[4];
#pragma unroll
        for (int mt = 0; mt < 4; ++mt)
            af[mt] = *(const bf16x8*)(As + (wm * 64 + mt * 16 + n16) * 40 + quad * 8);
#pragma unroll
        for (int nt = 0; nt < 4; ++nt)
            bf[nt] = *(const bf16x8*)(Bs + (wn * 64 + nt * 16 + n16) * 40 + quad * 8);
#pragma unroll
        for (int mt = 0; mt < 4; ++mt)
#pragma unroll
            for (int nt = 0; nt < 4; ++nt)
                acc[mt][nt] = mfma16(af[mt], bf[nt], acc[mt][nt]);
    }

#pragma unroll
    for (int mt = 0; mt < 4; ++mt)
#pragma unroll
        for (int nt = 0; nt < 4; ++nt)
#pragma unroll
            for (int r = 0; r < 4; ++r) {
                int m = m0 + wm * 64 + mt * 16 + quad * 4 + r;
                int n = n0 + wn * 64 + nt * 16 + n16;
                int b = m >> 11, i = m & 2047;
                int sg = n >> 9, cc = n & 511;
                int h = cc >> 6, d = cc & 63;
                size_t bh = (size_t)(b * NH + h);
                float fv = acc[mt][nt][r];
                if (sg == 0)      q[(bh * NN + i) * HD + d] = (__bf16)(fv * SCALE);
                else if (sg == 1) kk[(bh * NN + i) * HD + d] = (__bf16)fv;
                else              vT[(bh * HD + d) * NN + i] = (__bf16)fv;
            }
}

// ---------------------------------------------------------------------------
// Kernel D: flash attention, split-j x2, fixed softmax reference point (m=0).
// Block = (b, h, 64 q-rows, jsplit), 4 waves. Writes unnormalized O (bf16)
// and partial l (fp32).
// ---------------------------------------------------------------------------
__global__ __launch_bounds__(256, 4) void flash_attn(const __bf16* __restrict__ qb,
                                                     const __bf16* __restrict__ kb,
                                                     const __bf16* __restrict__ vTb,
                                                     const __bf16* __restrict__ maskb,
                                                     __bf16* __restrict__ Opart,
                                                     float* __restrict__ lpart) {
    __shared__ __bf16 Ks[64][72];   // rows j-local, cols d
    __shared__ __bf16 Vs[64][72];   // rows d,       cols j-local
    __shared__ __bf16 Ps[64][72];   // rows i-local, cols j-local
    __shared__ float Lrow[64];

    const int t = threadIdx.x;
    const int lane = t & 63;
    const int w = t >> 6;           // wave -> 16-row i-strip
    const int n16 = lane & 15;
    const int quad = lane >> 4;

    const int blk = blockIdx.x;
    const int split = blk & 1;
    const int it = (blk >> 1) & 31;
    const int h = (blk >> 6) & 7;
    const int b = blk >> 9;
    const int i0 = it * 64;
    const int bh = b * NH + h;

    // Q fragments (serve as MFMA B-operand for S^T = K * Q^T)
    bf16x8 qfrag[2];
    {
        const __bf16* qrow = qb + ((size_t)bh * NN + i0 + w * 16 + n16) * HD;
        qfrag[0] = *(const bf16x8*)(qrow + quad * 8);
        qfrag[1] = *(const bf16x8*)(qrow + 32 + quad * 8);
    }

    floatx4 O[4];
#pragma unroll
    for (int dt = 0; dt < 4; ++dt) O[dt] = (floatx4){0.f, 0.f, 0.f, 0.f};
    float lp = 0.f;   // lane-local partial row-sum (row i = i0 + w*16 + n16)

    const int srow = t >> 3, sseg = t & 7;
    const __bf16* kg = kb + (size_t)bh * NN * HD;
    const __bf16* vg = vTb + (size_t)bh * HD * NN;
    const __bf16* mbase = maskb + ((size_t)b * NN + i0 + w * 16 + n16) * NN;

    int j0 = split * (NN / 2);
    // prefetch first tile
    float4 k1 = *(const float4*)(kg + (size_t)(j0 + srow) * HD + sseg * 8);
    float4 k2 = *(const float4*)(kg + (size_t)(j0 + srow + 32) * HD + sseg * 8);
    float4 v1 = *(const float4*)(vg + (size_t)srow * NN + j0 + sseg * 8);
    float4 v2 = *(const float4*)(vg + (size_t)(srow + 32) * NN + j0 + sseg * 8);

    for (int iter = 0; iter < (NN / 2) / 64; ++iter, j0 += 64) {
        __syncthreads();            // prior-iter LDS reads complete
        *(float4*)(&Ks[srow][sseg * 8]) = k1;
        *(float4*)(&Ks[srow + 32][sseg * 8]) = k2;
        *(float4*)(&Vs[srow][sseg * 8]) = v1;
        *(float4*)(&Vs[srow + 32][sseg * 8]) = v2;
        __syncthreads();
        if (iter + 1 < (NN / 2) / 64) {
            int jn = j0 + 64;
            k1 = *(const float4*)(kg + (size_t)(jn + srow) * HD + sseg * 8);
            k2 = *(const float4*)(kg + (size_t)(jn + srow + 32) * HD + sseg * 8);
            v1 = *(const float4*)(vg + (size_t)srow * NN + jn + sseg * 8);
            v2 = *(const float4*)(vg + (size_t)(srow + 32) * NN + jn + sseg * 8);
        }
        // mask loads, direct from global in S^T C-layout (4 consecutive j/lane)
        ushort4 mu[4];
        const __bf16* mrow = mbase + j0 + quad * 4;
#pragma unroll
        for (int jt = 0; jt < 4; ++jt)
            mu[jt] = *(const ushort4*)(mrow + jt * 16);

        // S^T = K * Q^T: lane holds S[i=n16][j = jt*16 + quad*4 + r]
        floatx4 S[4];
#pragma unroll
        for (int jt = 0; jt < 4; ++jt) {
            floatx4 acc = (floatx4){0.f, 0.f, 0.f, 0.f};
            bf16x8 kf0 = *(const bf16x8*)(&Ks[jt * 16 + n16][quad * 8]);
            bf16x8 kf1 = *(const bf16x8*)(&Ks[jt * 16 + n16][32 + quad * 8]);
            acc = mfma16(kf0, qfrag[0], acc);
            acc = mfma16(kf1, qfrag[1], acc);
            S[jt] = acc;
        }

        // p = exp(mask * s)  (no max subtraction: |s| <= ~0.05, provably safe)
#pragma unroll
        for (int jt = 0; jt < 4; ++jt) {
            float p0 = __expf(S[jt][0] * bf2f(mu[jt].x));
            float p1 = __expf(S[jt][1] * bf2f(mu[jt].y));
            float p2 = __expf(S[jt][2] * bf2f(mu[jt].z));
            float p3 = __expf(S[jt][3] * bf2f(mu[jt].w));
            lp += (p0 + p1) + (p2 + p3);
            bf16x4 pk;
            pk[0] = (__bf16)p0; pk[1] = (__bf16)p1;
            pk[2] = (__bf16)p2; pk[3] = (__bf16)p3;
            *(bf16x4*)(&Ps[w * 16 + n16][jt * 16 + quad * 4]) = pk;   // wave-local
        }

        // PV: O[i][d] += P[i][j] V[j][d]  (Ps rows are wave-local: no barrier)
        bf16x8 pf0 = *(const bf16x8*)(&Ps[w * 16 + n16][quad * 8]);
        bf16x8 pf1 = *(const bf16x8*)(&Ps[w * 16 + n16][32 + quad * 8]);
#pragma unroll
        for (int dt = 0; dt < 4; ++dt) {
            bf16x8 vf0 = *(const bf16x8*)(&Vs[dt * 16 + n16][quad * 8]);
            bf16x8 vf1 = *(const bf16x8*)(&Vs[dt * 16 + n16][32 + quad * 8]);
            O[dt] = mfma16(pf0, vf0, O[dt]);
            O[dt] = mfma16(pf1, vf1, O[dt]);
        }
    }

    // ---- epilogue: write unnormalized O (bf16) + partial l (fp32) ----
    lp += __shfl_xor(lp, 16);
    lp += __shfl_xor(lp, 32);
    const size_t sb = (size_t)(split * BB * NH + bh);
    if (quad == 0) {
        Lrow[w * 16 + n16] = lp;     // (unused, kept for symmetry)
        lpart[sb * NN + i0 + w * 16 + n16] = lp;
    }
#pragma unroll
    for (int dt = 0; dt < 4; ++dt)
#pragma unroll
        for (int r = 0; r < 4; ++r) {
            int i = i0 + w * 16 + quad * 4 + r;
            int d = dt * 16 + n16;
            Opart[(sb * NN + i) * HD + d] = (__bf16)O[dt][r];
        }
}

// ---------------------------------------------------------------------------
// Kernel D2: combine splits -> ohb [b, n, h*d] bf16
// ---------------------------------------------------------------------------
__global__ __launch_bounds__(256) void combine(const __bf16* __restrict__ Opart,
                                               const float* __restrict__ lpart,
                                               __bf16* __restrict__ ohb) {
    int g = blockIdx.x * 256 + threadIdx.x;      // 262144 threads
    int d0 = (g & 7) * 8;
    int n = (g >> 3) & 2047;
    int bh = g >> 14;                            // 0..15
    int b = bh >> 3, h = bh & 7;
    size_t idx0 = ((size_t)bh * NN + n) * HD + d0;
    size_t idx1 = ((size_t)(BB * NH + bh) * NN + n) * HD + d0;
    bf16x8 o0 = *(const bf16x8*)(Opart + idx0);
    bf16x8 o1 = *(const bf16x8*)(Opart + idx1);
    float l = lpart[(size_t)bh * NN + n] + lpart[(size_t)(BB * NH + bh) * NN + n];
    float inv = 1.0f / l;
    bf16x8 r;
#pragma unroll
    for (int e = 0; e < 8; ++e)
        r[e] = (__bf16)(((float)o0[e] + (float)o1[e]) * inv);
    *(bf16x8*)(ohb + ((size_t)b * NN + n) * (NH * HD) + h * HD + d0) = r;
}

// ---------------------------------------------------------------------------
// Kernel E: out = ohb @ w_out + b_out via MFMA. BM=64, BN=128 -> 256 blocks.
// ---------------------------------------------------------------------------
__global__ __launch_bounds__(256) void out_mfma(const __bf16* __restrict__ A,
                                                const __bf16* __restrict__ wT,
                                                const float* __restrict__ bias,
                                                float* __restrict__ out) {
    __shared__ __bf16 As[64 * 40];
    __shared__ __bf16 Bs[128 * 40];
    const int t = threadIdx.x;
    const int lane = t & 63, w = t >> 6;
    const int n16 = lane & 15, quad = lane >> 4;
    const int wm = w >> 1, wn = w & 1;
    const int m0 = blockIdx.y * 64, n0 = blockIdx.x * 128;
    const int ra = t >> 2, seg = t & 3;
    const int rb = t >> 2;

    floatx4 acc[2][4];
#pragma unroll
    for (int mt = 0; mt < 2; ++mt)
#pragma unroll
        for (int nt = 0; nt < 4; ++nt) acc[mt][nt] = (floatx4){0.f, 0.f, 0.f, 0.f};

    for (int k0 = 0; k0 < 512; k0 += 32) {
        bf16x8 a1 = *(const bf16x8*)(A + (size_t)(m0 + ra) * 512 + k0 + seg * 8);
        bf16x8 w1 = *(const bf16x8*)(wT + (size_t)(n0 + rb) * 512 + k0 + seg * 8);
        bf16x8 w2 = *(const bf16x8*)(wT + (size_t)(n0 + rb + 64) * 512 + k0 + seg * 8);
        __syncthreads();
        *(bf16x8*)(As + ra * 40 + seg * 8) = a1;
        *(bf16x8*)(Bs + rb * 40 + seg * 8) = w1;
        *(bf16x8*)(Bs + (rb + 64) * 40 + seg * 8) = w2;
        __syncthreads();
        bf16x8 af[2], bf[4];
#pragma unroll
        for (int mt = 0; mt < 2; ++mt)
            af[mt] = *(const bf16x8*)(As + (wm * 32 + mt * 16 + n16) * 40 + quad * 8);
#pragma unroll
        for (int nt = 0; nt < 4; ++nt)
            bf[nt] = *(const bf16x8*)(Bs + (wn * 64 + nt * 16 + n16) * 40 + quad * 8);
#pragma unroll
        for (int mt = 0; mt < 2; ++mt)
#pragma unroll
            for (int nt = 0; nt < 4; ++nt)
                acc[mt][nt] = mfma16(af[mt], bf[nt], acc[mt][nt]);
    }

#pragma unroll
    for (int mt = 0; mt < 2; ++mt)
#pragma unroll
        for (int nt = 0; nt < 4; ++nt)
#pragma unroll
            for (int r = 0; r < 4; ++r) {
                int m = m0 + wm * 32 + mt * 16 + quad * 4 + r;
                int n = n0 + wn * 64 + nt * 16 + n16;
                out[(size_t)m * 512 + n] = acc[mt][nt][r] + bias[n];
            }
}

extern "C" void kernel_launch(void* const* d_in, const int* in_sizes, int n_in,
                              void* d_out, int out_size, void* d_ws, size_t ws_size,
                              hipStream_t stream) {
    const float* x     = (const float*)d_in[0];
    const float* adj   = (const float*)d_in[1];
    const float* w_qkv = (const float*)d_in[2];
    const float* w_out = (const float*)d_in[3];
    const float* b_out = (const float*)d_in[4];
    float* out = (float*)d_out;
    char* wsb = (char*)d_ws;

    // workspace byte layout (~46.3 MiB). ohb aliases q (q dead after flash).
    __bf16* wqkvT = (__bf16*)(wsb + 0);                  // 1.5 MiB
    __bf16* woutT = (__bf16*)(wsb + (3u << 19));         // 0.5 MiB
    __bf16* q     = (__bf16*)(wsb + (2u << 20));         // 4 MiB
    __bf16* ohb   = (__bf16*)(wsb + (2u << 20));         // aliases q
    __bf16* k     = (__bf16*)(wsb + (6u << 20));         // 4 MiB
    __bf16* vT    = (__bf16*)(wsb + (10u << 20));        // 4 MiB
    __bf16* mask  = (__bf16*)(wsb + (14u << 20));        // 16 MiB
    __bf16* Opart = (__bf16*)(wsb + (30u << 20));        // 16 MiB (2 splits)
    float*  lpart = (float*) (wsb + (46u << 20));        // 256 KiB

    adj_softmax<<<BB * NN, 256, 0, stream>>>(adj, mask);
    tcast_w<<<dim3(1536 / 32, 512 / 32), 256, 0, stream>>>(w_qkv, wqkvT, 512, 1536);
    tcast_w<<<dim3(512 / 32, 512 / 32), 256, 0, stream>>>(w_out, woutT, 512, 512);
    qkv_mfma<<<dim3(1536 / 128, 4096 / 128), 256, 0, stream>>>(x, wqkvT, q, k, vT);
    flash_attn<<<BB * NH * 32 * 2, 256, 0, stream>>>(q, k, vT, mask, Opart, lpart);
    combine<<<1024, 256, 0, stream>>>(Opart, lpart, ohb);
    out_mfma<<<dim3(512 / 128, 4096 / 64), 256, 0, stream>>>(ohb, woutT, b_out, out);
}

// Round 5
// 175.695 us; speedup vs baseline: 3.8537x; 1.0345x over previous
//
#include <hip/hip_runtime.h>
#include <hip/hip_bf16.h>
#include <math.h>

// Problem constants
#define BB 2
#define NN 2048
#define DIM 512
#define NH 8
#define HD 64
#define SCALE 0.125f

typedef __bf16 bf16x8 __attribute__((ext_vector_type(8)));
typedef __bf16 bf16x4 __attribute__((ext_vector_type(4)));
typedef float floatx4 __attribute__((ext_vector_type(4)));

static inline __device__ floatx4 mfma16(bf16x8 a, bf16x8 b, floatx4 c) {
    return __builtin_amdgcn_mfma_f32_16x16x32_bf16(a, b, c, 0, 0, 0);
}

static inline __device__ bf16x8 cvt8(float4 a, float4 b) {
    bf16x8 r;
    r[0] = (__bf16)a.x; r[1] = (__bf16)a.y; r[2] = (__bf16)a.z; r[3] = (__bf16)a.w;
    r[4] = (__bf16)b.x; r[5] = (__bf16)b.y; r[6] = (__bf16)b.z; r[7] = (__bf16)b.w;
    return r;
}

static inline __device__ float bf2f(unsigned short u) {
    return __uint_as_float(((unsigned)u) << 16);
}

// async global->LDS, 16 B per lane; lds must be wave-uniform
static inline __device__ void dma16(const void* g, void* l) {
    __builtin_amdgcn_global_load_lds(
        (const __attribute__((address_space(1))) unsigned int*)g,
        (__attribute__((address_space(3))) unsigned int*)l,
        16, 0, 0);
}

// ---------------------------------------------------------------------------
// Kernel A: fused softmax(adj) rows -> bf16 mask (float4 loads)
// ---------------------------------------------------------------------------
__global__ __launch_bounds__(256) void adj_softmax(const float* __restrict__ adj,
                                                   __bf16* __restrict__ mask) {
    int row = blockIdx.x;                 // b*NN + i
    const float* a = adj + (size_t)row * NN;
    __bf16* m = mask + (size_t)row * NN;
    int t = threadIdx.x;
    float4 va = *(const float4*)(a + 4 * t);
    float4 vb = *(const float4*)(a + 1024 + 4 * t);
    float v[8] = {va.x, va.y, va.z, va.w, vb.x, vb.y, vb.z, vb.w};
    float mx = -INFINITY;
#pragma unroll
    for (int c = 0; c < 8; ++c) mx = fmaxf(mx, v[c]);
    __shared__ float red[256];
    red[t] = mx; __syncthreads();
    for (int s = 128; s > 0; s >>= 1) {
        if (t < s) red[t] = fmaxf(red[t], red[t + s]);
        __syncthreads();
    }
    mx = red[0]; __syncthreads();
    float sm = 0.f;
    float e[8];
#pragma unroll
    for (int c = 0; c < 8; ++c) { e[c] = __expf(v[c] - mx); sm += e[c]; }
    red[t] = sm; __syncthreads();
    for (int s = 128; s > 0; s >>= 1) {
        if (t < s) red[t] += red[t + s];
        __syncthreads();
    }
    float inv = 1.0f / red[0];
    bf16x4 o0, o1;
#pragma unroll
    for (int c = 0; c < 4; ++c) { o0[c] = (__bf16)(e[c] * inv); o1[c] = (__bf16)(e[c + 4] * inv); }
    *(bf16x4*)(m + 4 * t) = o0;
    *(bf16x4*)(m + 1024 + 4 * t) = o1;
}

// ---------------------------------------------------------------------------
// Kernel A2: cast x fp32 -> bf16 (row-major, unchanged layout)
// ---------------------------------------------------------------------------
__global__ __launch_bounds__(256) void xcast(const float* __restrict__ x,
                                             __bf16* __restrict__ xb) {
    int g = blockIdx.x * 256 + threadIdx.x;   // 262144 threads * 8 elems
    float4 f0 = ((const float4*)x)[2 * (size_t)g];
    float4 f1 = ((const float4*)x)[2 * (size_t)g + 1];
    *(bf16x8*)(xb + 8 * (size_t)g) = cvt8(f0, f1);
}

// ---------------------------------------------------------------------------
// Kernel B: transpose + cast weight  w[K][N] fp32 -> wT[N][K] bf16
// ---------------------------------------------------------------------------
__global__ __launch_bounds__(256) void tcast_w(const float* __restrict__ w,
                                               __bf16* __restrict__ wT,
                                               int K, int N) {
    __shared__ float tile[32][33];
    int n0 = blockIdx.x * 32, k0 = blockIdx.y * 32;
    int c = threadIdx.x & 31, r = threadIdx.x >> 5;   // r in 0..7
#pragma unroll
    for (int p = 0; p < 4; ++p)
        tile[r + p * 8][c] = w[(size_t)(k0 + r + p * 8) * N + n0 + c];
    __syncthreads();
#pragma unroll
    for (int p = 0; p < 4; ++p)
        wT[(size_t)(n0 + r + p * 8) * K + k0 + c] = (__bf16)tile[c][r + p * 8];
}

// ---------------------------------------------------------------------------
// Kernel C: qkv = xb @ w_qkv via MFMA + global_load_lds staging.
// BM=128, BN=64, BK=32; grid (24,32)=768 blocks; 4 waves (2 m-strips x 2 n-strips).
// LDS layout: unpadded [row][32], chunk c holds global chunk c^(r&3) (XOR swizzle).
// q gets SCALE folded in.
// ---------------------------------------------------------------------------
__global__ __launch_bounds__(256) void qkv_mfma(const __bf16* __restrict__ xb,
                                                const __bf16* __restrict__ wT,
                                                __bf16* __restrict__ q,
                                                __bf16* __restrict__ kk,
                                                __bf16* __restrict__ vT) {
    __shared__ __bf16 As[128 * 32];   // 8 KB
    __shared__ __bf16 Bs[64 * 32];    // 4 KB
    const int t = threadIdx.x;
    const int lane = t & 63, w = t >> 6;
    const int n16 = lane & 15, quad = lane >> 4;
    const int wm = w >> 1, wn = w & 1;
    const int m0 = blockIdx.y * 128, n0 = blockIdx.x * 64;

    // DMA source mapping: LDS byte o = t*16 -> row = t>>2, chunk = t&3;
    // fetch global chunk (t&3) ^ ((t>>2)&3)
    const int drow = t >> 2;
    const int dchunk = (t & 3) ^ (drow & 3);
    char* ldsA = (char*)As + (t >> 6) * 1024;
    char* ldsB = (char*)Bs + (t >> 6) * 1024;

    floatx4 acc[4][2];
#pragma unroll
    for (int mt = 0; mt < 4; ++mt)
#pragma unroll
        for (int nt = 0; nt < 2; ++nt) acc[mt][nt] = (floatx4){0.f, 0.f, 0.f, 0.f};

    const int swz = n16 & 3;   // read-side XOR for fragment rows (row&3 == n16&3)

    for (int k0 = 0; k0 < 512; k0 += 32) {
        __syncthreads();
        dma16(xb + (size_t)(m0 + drow) * 512 + k0 + dchunk * 8, ldsA);
        dma16(xb + (size_t)(m0 + 64 + drow) * 512 + k0 + dchunk * 8, (char*)As + 4096 + (t >> 6) * 1024);
        dma16(wT + (size_t)(n0 + drow) * 512 + k0 + dchunk * 8, ldsB);
        __syncthreads();
        bf16x8 af[4], bf[2];
#pragma unroll
        for (int mt = 0; mt < 4; ++mt)
            af[mt] = *(const bf16x8*)(As + (wm * 64 + mt * 16 + n16) * 32 + (quad ^ swz) * 8);
#pragma unroll
        for (int nt = 0; nt < 2; ++nt)
            bf[nt] = *(const bf16x8*)(Bs + (wn * 32 + nt * 16 + n16) * 32 + (quad ^ swz) * 8);
#pragma unroll
        for (int mt = 0; mt < 4; ++mt)
#pragma unroll
            for (int nt = 0; nt < 2; ++nt)
                acc[mt][nt] = mfma16(af[mt], bf[nt], acc[mt][nt]);
    }

    // scatter epilogue (seg/h uniform per block: 64-col tile within one 512 segment)
#pragma unroll
    for (int mt = 0; mt < 4; ++mt)
#pragma unroll
        for (int nt = 0; nt < 2; ++nt)
#pragma unroll
            for (int r = 0; r < 4; ++r) {
                int m = m0 + wm * 64 + mt * 16 + quad * 4 + r;
                int n = n0 + wn * 32 + nt * 16 + n16;
                int b = m >> 11, i = m & 2047;
                int sg = n >> 9, cc = n & 511;
                int h = cc >> 6, d = cc & 63;
                size_t bh = (size_t)(b * NH + h);
                float fv = acc[mt][nt][r];
                if (sg == 0)      q[(bh * NN + i) * HD + d] = (__bf16)(fv * SCALE);
                else if (sg == 1) kk[(bh * NN + i) * HD + d] = (__bf16)fv;
                else              vT[(bh * HD + d) * NN + i] = (__bf16)fv;
            }
}

// ---------------------------------------------------------------------------
// Kernel D: flash attention, split-j x4, fixed softmax reference (m=0).
// Block = (b, h, 64 q-rows, jsplit), 4 waves; 8 j-iters of 64.
// ---------------------------------------------------------------------------
__global__ __launch_bounds__(256, 4) void flash_attn(const __bf16* __restrict__ qb,
                                                     const __bf16* __restrict__ kb,
                                                     const __bf16* __restrict__ vTb,
                                                     const __bf16* __restrict__ maskb,
                                                     __bf16* __restrict__ Opart,
                                                     float* __restrict__ lpart) {
    __shared__ __bf16 Ks[64][72];   // rows j-local, cols d
    __shared__ __bf16 Vs[64][72];   // rows d,       cols j-local
    __shared__ __bf16 Ps[64][72];   // rows i-local, cols j-local

    const int t = threadIdx.x;
    const int lane = t & 63;
    const int w = t >> 6;           // wave -> 16-row i-strip
    const int n16 = lane & 15;
    const int quad = lane >> 4;

    const int blk = blockIdx.x;
    const int split = blk & 3;
    const int it = (blk >> 2) & 31;
    const int h = (blk >> 7) & 7;
    const int b = blk >> 10;
    const int i0 = it * 64;
    const int bh = b * NH + h;

    bf16x8 qfrag[2];
    {
        const __bf16* qrow = qb + ((size_t)bh * NN + i0 + w * 16 + n16) * HD;
        qfrag[0] = *(const bf16x8*)(qrow + quad * 8);
        qfrag[1] = *(const bf16x8*)(qrow + 32 + quad * 8);
    }

    floatx4 O[4];
#pragma unroll
    for (int dt = 0; dt < 4; ++dt) O[dt] = (floatx4){0.f, 0.f, 0.f, 0.f};
    float lp = 0.f;

    const int srow = t >> 3, sseg = t & 7;
    const __bf16* kg = kb + (size_t)bh * NN * HD;
    const __bf16* vg = vTb + (size_t)bh * HD * NN;
    const __bf16* mbase = maskb + ((size_t)b * NN + i0 + w * 16 + n16) * NN;

    int j0 = split * (NN / 4);
    float4 k1 = *(const float4*)(kg + (size_t)(j0 + srow) * HD + sseg * 8);
    float4 k2 = *(const float4*)(kg + (size_t)(j0 + srow + 32) * HD + sseg * 8);
    float4 v1 = *(const float4*)(vg + (size_t)srow * NN + j0 + sseg * 8);
    float4 v2 = *(const float4*)(vg + (size_t)(srow + 32) * NN + j0 + sseg * 8);

    for (int iter = 0; iter < (NN / 4) / 64; ++iter, j0 += 64) {
        __syncthreads();
        *(float4*)(&Ks[srow][sseg * 8]) = k1;
        *(float4*)(&Ks[srow + 32][sseg * 8]) = k2;
        *(float4*)(&Vs[srow][sseg * 8]) = v1;
        *(float4*)(&Vs[srow + 32][sseg * 8]) = v2;
        __syncthreads();
        if (iter + 1 < (NN / 4) / 64) {
            int jn = j0 + 64;
            k1 = *(const float4*)(kg + (size_t)(jn + srow) * HD + sseg * 8);
            k2 = *(const float4*)(kg + (size_t)(jn + srow + 32) * HD + sseg * 8);
            v1 = *(const float4*)(vg + (size_t)srow * NN + jn + sseg * 8);
            v2 = *(const float4*)(vg + (size_t)(srow + 32) * NN + jn + sseg * 8);
        }
        ushort4 mu[4];
        const __bf16* mrow = mbase + j0 + quad * 4;
#pragma unroll
        for (int jt = 0; jt < 4; ++jt)
            mu[jt] = *(const ushort4*)(mrow + jt * 16);

        // S^T = K * Q^T: lane holds S[i=n16][j = jt*16 + quad*4 + r]
        floatx4 S[4];
#pragma unroll
        for (int jt = 0; jt < 4; ++jt) {
            floatx4 acc = (floatx4){0.f, 0.f, 0.f, 0.f};
            bf16x8 kf0 = *(const bf16x8*)(&Ks[jt * 16 + n16][quad * 8]);
            bf16x8 kf1 = *(const bf16x8*)(&Ks[jt * 16 + n16][32 + quad * 8]);
            acc = mfma16(kf0, qfrag[0], acc);
            acc = mfma16(kf1, qfrag[1], acc);
            S[jt] = acc;
        }

        // p = exp(mask * s); |s| <= ~0.05 so no max subtraction needed
#pragma unroll
        for (int jt = 0; jt < 4; ++jt) {
            float p0 = __expf(S[jt][0] * bf2f(mu[jt].x));
            float p1 = __expf(S[jt][1] * bf2f(mu[jt].y));
            float p2 = __expf(S[jt][2] * bf2f(mu[jt].z));
            float p3 = __expf(S[jt][3] * bf2f(mu[jt].w));
            lp += (p0 + p1) + (p2 + p3);
            bf16x4 pk;
            pk[0] = (__bf16)p0; pk[1] = (__bf16)p1;
            pk[2] = (__bf16)p2; pk[3] = (__bf16)p3;
            *(bf16x4*)(&Ps[w * 16 + n16][jt * 16 + quad * 4]) = pk;   // wave-local
        }

        bf16x8 pf0 = *(const bf16x8*)(&Ps[w * 16 + n16][quad * 8]);
        bf16x8 pf1 = *(const bf16x8*)(&Ps[w * 16 + n16][32 + quad * 8]);
#pragma unroll
        for (int dt = 0; dt < 4; ++dt) {
            bf16x8 vf0 = *(const bf16x8*)(&Vs[dt * 16 + n16][quad * 8]);
            bf16x8 vf1 = *(const bf16x8*)(&Vs[dt * 16 + n16][32 + quad * 8]);
            O[dt] = mfma16(pf0, vf0, O[dt]);
            O[dt] = mfma16(pf1, vf1, O[dt]);
        }
    }

    lp += __shfl_xor(lp, 16);
    lp += __shfl_xor(lp, 32);
    const size_t sb = (size_t)(split * BB * NH + bh);
    if (quad == 0)
        lpart[sb * NN + i0 + w * 16 + n16] = lp;
#pragma unroll
    for (int dt = 0; dt < 4; ++dt)
#pragma unroll
        for (int r = 0; r < 4; ++r) {
            int i = i0 + w * 16 + quad * 4 + r;
            int d = dt * 16 + n16;
            Opart[(sb * NN + i) * HD + d] = (__bf16)O[dt][r];
        }
}

// ---------------------------------------------------------------------------
// Kernel D2: combine 4 splits -> ohb [b, n, h*d] bf16
// ---------------------------------------------------------------------------
__global__ __launch_bounds__(256) void combine(const __bf16* __restrict__ Opart,
                                               const float* __restrict__ lpart,
                                               __bf16* __restrict__ ohb) {
    int g = blockIdx.x * 256 + threadIdx.x;      // 262144 threads
    int d0 = (g & 7) * 8;
    int n = (g >> 3) & 2047;
    int bh = g >> 14;                            // 0..15
    int b = bh >> 3, h = bh & 7;
    float o[8] = {};
    float l = 0.f;
#pragma unroll
    for (int s = 0; s < 4; ++s) {
        size_t sb = (size_t)(s * BB * NH + bh);
        bf16x8 ov = *(const bf16x8*)(Opart + (sb * NN + n) * HD + d0);
#pragma unroll
        for (int e = 0; e < 8; ++e) o[e] += (float)ov[e];
        l += lpart[sb * NN + n];
    }
    float inv = 1.0f / l;
    bf16x8 r;
#pragma unroll
    for (int e = 0; e < 8; ++e) r[e] = (__bf16)(o[e] * inv);
    *(bf16x8*)(ohb + ((size_t)b * NN + n) * (NH * HD) + h * HD + d0) = r;
}

// ---------------------------------------------------------------------------
// Kernel E: out = ohb @ w_out + b_out via MFMA + DMA staging.
// BM=64, BN=128, BK=32; grid (4,64)=256 blocks; 4 waves (2x2).
// ---------------------------------------------------------------------------
__global__ __launch_bounds__(256) void out_mfma(const __bf16* __restrict__ A,
                                                const __bf16* __restrict__ wT,
                                                const float* __restrict__ bias,
                                                float* __restrict__ out) {
    __shared__ __bf16 As[64 * 32];    // 4 KB
    __shared__ __bf16 Bs[128 * 32];   // 8 KB
    const int t = threadIdx.x;
    const int lane = t & 63, w = t >> 6;
    const int n16 = lane & 15, quad = lane >> 4;
    const int wm = w >> 1, wn = w & 1;     // wave tile: 32 rows x 64 cols
    const int m0 = blockIdx.y * 64, n0 = blockIdx.x * 128;

    const int drow = t >> 2;
    const int dchunk = (t & 3) ^ (drow & 3);
    char* ldsA = (char*)As + (t >> 6) * 1024;
    char* ldsB = (char*)Bs + (t >> 6) * 1024;
    const int swz = n16 & 3;

    floatx4 acc[2][4];
#pragma unroll
    for (int mt = 0; mt < 2; ++mt)
#pragma unroll
        for (int nt = 0; nt < 4; ++nt) acc[mt][nt] = (floatx4){0.f, 0.f, 0.f, 0.f};

    for (int k0 = 0; k0 < 512; k0 += 32) {
        __syncthreads();
        dma16(A + (size_t)(m0 + drow) * 512 + k0 + dchunk * 8, ldsA);
        dma16(wT + (size_t)(n0 + drow) * 512 + k0 + dchunk * 8, ldsB);
        dma16(wT + (size_t)(n0 + 64 + drow) * 512 + k0 + dchunk * 8, (char*)Bs + 4096 + (t >> 6) * 1024);
        __syncthreads();
        bf16x8 af[2], bf[4];
#pragma unroll
        for (int mt = 0; mt < 2; ++mt)
            af[mt] = *(const bf16x8*)(As + (wm * 32 + mt * 16 + n16) * 32 + (quad ^ swz) * 8);
#pragma unroll
        for (int nt = 0; nt < 4; ++nt)
            bf[nt] = *(const bf16x8*)(Bs + (wn * 64 + nt * 16 + n16) * 32 + (quad ^ swz) * 8);
#pragma unroll
        for (int mt = 0; mt < 2; ++mt)
#pragma unroll
            for (int nt = 0; nt < 4; ++nt)
                acc[mt][nt] = mfma16(af[mt], bf[nt], acc[mt][nt]);
    }

#pragma unroll
    for (int mt = 0; mt < 2; ++mt)
#pragma unroll
        for (int nt = 0; nt < 4; ++nt)
#pragma unroll
            for (int r = 0; r < 4; ++r) {
                int m = m0 + wm * 32 + mt * 16 + quad * 4 + r;
                int n = n0 + wn * 64 + nt * 16 + n16;
                out[(size_t)m * 512 + n] = acc[mt][nt][r] + bias[n];
            }
}

extern "C" void kernel_launch(void* const* d_in, const int* in_sizes, int n_in,
                              void* d_out, int out_size, void* d_ws, size_t ws_size,
                              hipStream_t stream) {
    const float* x     = (const float*)d_in[0];
    const float* adj   = (const float*)d_in[1];
    const float* w_qkv = (const float*)d_in[2];
    const float* w_out = (const float*)d_in[3];
    const float* b_out = (const float*)d_in[4];
    float* out = (float*)d_out;
    char* wsb = (char*)d_ws;

    // workspace byte layout (46.5 MiB total)
    __bf16* wqkvT = (__bf16*)(wsb + 0);                  // 1.5 MiB
    __bf16* woutT = (__bf16*)(wsb + (3u << 19));         // 0.5 MiB
    __bf16* q     = (__bf16*)(wsb + (2u << 20));         // 4 MiB
    __bf16* ohb   = (__bf16*)(wsb + (2u << 20));         // aliases q (q dead at combine)
    __bf16* k     = (__bf16*)(wsb + (6u << 20));         // 4 MiB
    __bf16* vT    = (__bf16*)(wsb + (10u << 20));        // 4 MiB
    __bf16* mask  = (__bf16*)(wsb + (14u << 20));        // 16 MiB
    __bf16* Opart = (__bf16*)(wsb + (30u << 20));        // 16 MiB (4 splits)
    __bf16* xb    = (__bf16*)(wsb + (30u << 20));        // aliases Opart[0:4MiB] (dead after qkv)
    float*  lpart = (float*) (wsb + (46u << 20));        // 512 KiB

    adj_softmax<<<BB * NN, 256, 0, stream>>>(adj, mask);
    xcast<<<1024, 256, 0, stream>>>(x, xb);
    tcast_w<<<dim3(1536 / 32, 512 / 32), 256, 0, stream>>>(w_qkv, wqkvT, 512, 1536);
    tcast_w<<<dim3(512 / 32, 512 / 32), 256, 0, stream>>>(w_out, woutT, 512, 512);
    qkv_mfma<<<dim3(1536 / 64, 4096 / 128), 256, 0, stream>>>(xb, wqkvT, q, k, vT);
    flash_attn<<<BB * NH * 32 * 4, 256, 0, stream>>>(q, k, vT, mask, Opart, lpart);
    combine<<<1024, 256, 0, stream>>>(Opart, lpart, ohb);
    out_mfma<<<dim3(512 / 128, 4096 / 64), 256, 0, stream>>>(ohb, woutT, b_out, out);
}

// Round 6
// 165.598 us; speedup vs baseline: 4.0887x; 1.0610x over previous
//
#include <hip/hip_runtime.h>
#include <hip/hip_bf16.h>
#include <math.h>

// Problem constants
#define BB 2
#define NN 2048
#define DIM 512
#define NH 8
#define HD 64
#define SCALE 0.125f

typedef __bf16 bf16x8 __attribute__((ext_vector_type(8)));
typedef __bf16 bf16x4 __attribute__((ext_vector_type(4)));
typedef float floatx4 __attribute__((ext_vector_type(4)));

static inline __device__ floatx4 mfma16(bf16x8 a, bf16x8 b, floatx4 c) {
    return __builtin_amdgcn_mfma_f32_16x16x32_bf16(a, b, c, 0, 0, 0);
}

static inline __device__ bf16x8 cvt8(float4 a, float4 b) {
    bf16x8 r;
    r[0] = (__bf16)a.x; r[1] = (__bf16)a.y; r[2] = (__bf16)a.z; r[3] = (__bf16)a.w;
    r[4] = (__bf16)b.x; r[5] = (__bf16)b.y; r[6] = (__bf16)b.z; r[7] = (__bf16)b.w;
    return r;
}

static inline __device__ float bf2f(unsigned short u) {
    return __uint_as_float(((unsigned)u) << 16);
}

// async global->LDS, 16 B per lane; lds base must be wave-uniform
static inline __device__ void dma16(const void* g, void* l) {
    __builtin_amdgcn_global_load_lds(
        (const __attribute__((address_space(1))) unsigned int*)g,
        (__attribute__((address_space(3))) unsigned int*)l,
        16, 0, 0);
}

// ---------------------------------------------------------------------------
// Kernel A: fused softmax(adj) rows -> bf16 mask; wave-shuffle reductions
// ---------------------------------------------------------------------------
__global__ __launch_bounds__(256) void adj_softmax(const float* __restrict__ adj,
                                                   __bf16* __restrict__ mask) {
    int row = blockIdx.x;                 // b*NN + i
    const float* a = adj + (size_t)row * NN;
    __bf16* m = mask + (size_t)row * NN;
    int t = threadIdx.x;
    int w = t >> 6, lane = t & 63;
    float4 va = *(const float4*)(a + 4 * t);
    float4 vb = *(const float4*)(a + 1024 + 4 * t);
    float v[8] = {va.x, va.y, va.z, va.w, vb.x, vb.y, vb.z, vb.w};
    float mx = -INFINITY;
#pragma unroll
    for (int c = 0; c < 8; ++c) mx = fmaxf(mx, v[c]);
#pragma unroll
    for (int s = 1; s < 64; s <<= 1) mx = fmaxf(mx, __shfl_xor(mx, s));
    __shared__ float red[8];
    if (lane == 0) red[w] = mx;
    __syncthreads();
    mx = fmaxf(fmaxf(red[0], red[1]), fmaxf(red[2], red[3]));
    float sm = 0.f;
    float e[8];
#pragma unroll
    for (int c = 0; c < 8; ++c) { e[c] = __expf(v[c] - mx); sm += e[c]; }
#pragma unroll
    for (int s = 1; s < 64; s <<= 1) sm += __shfl_xor(sm, s);
    if (lane == 0) red[4 + w] = sm;
    __syncthreads();
    float inv = 1.0f / ((red[4] + red[5]) + (red[6] + red[7]));
    bf16x4 o0, o1;
#pragma unroll
    for (int c = 0; c < 4; ++c) { o0[c] = (__bf16)(e[c] * inv); o1[c] = (__bf16)(e[c + 4] * inv); }
    *(bf16x4*)(m + 4 * t) = o0;
    *(bf16x4*)(m + 1024 + 4 * t) = o1;
}

// ---------------------------------------------------------------------------
// Kernel A2: cast x fp32 -> bf16
// ---------------------------------------------------------------------------
__global__ __launch_bounds__(256) void xcast(const float* __restrict__ x,
                                             __bf16* __restrict__ xb) {
    int g = blockIdx.x * 256 + threadIdx.x;
    float4 f0 = ((const float4*)x)[2 * (size_t)g];
    float4 f1 = ((const float4*)x)[2 * (size_t)g + 1];
    *(bf16x8*)(xb + 8 * (size_t)g) = cvt8(f0, f1);
}

// ---------------------------------------------------------------------------
// Kernel B: transpose + cast weight  w[K][N] fp32 -> wT[N][K] bf16
// ---------------------------------------------------------------------------
__global__ __launch_bounds__(256) void tcast_w(const float* __restrict__ w,
                                               __bf16* __restrict__ wT,
                                               int K, int N) {
    __shared__ float tile[32][33];
    int n0 = blockIdx.x * 32, k0 = blockIdx.y * 32;
    int c = threadIdx.x & 31, r = threadIdx.x >> 5;
#pragma unroll
    for (int p = 0; p < 4; ++p)
        tile[r + p * 8][c] = w[(size_t)(k0 + r + p * 8) * N + n0 + c];
    __syncthreads();
#pragma unroll
    for (int p = 0; p < 4; ++p)
        wT[(size_t)(n0 + r + p * 8) * K + k0 + c] = (__bf16)tile[c][r + p * 8];
}

// ---------------------------------------------------------------------------
// Kernel C: qkv = xb @ w_qkv via MFMA + DMA staging.
// BM=128, BN=64, BK=64; grid (24,32)=768 blocks (3/CU even); 4 waves (2x2).
// LDS rows 128 B (= 32 banks); XOR swizzle key (row&7): store LDS chunk c of
// row R holds global chunk c^(R&7); reads land worst 2-way (free, m136).
// q gets SCALE folded in.
// ---------------------------------------------------------------------------
__global__ __launch_bounds__(256) void qkv_mfma(const __bf16* __restrict__ xb,
                                                const __bf16* __restrict__ wT,
                                                __bf16* __restrict__ q,
                                                __bf16* __restrict__ kk,
                                                __bf16* __restrict__ vT) {
    __shared__ __bf16 As[128 * 64];   // 16 KB
    __shared__ __bf16 Bs[64 * 64];    // 8 KB
    const int t = threadIdx.x;
    const int lane = t & 63, w = t >> 6;
    const int n16 = lane & 15, quad = lane >> 4;
    const int wm = w >> 1, wn = w & 1;
    const int m0 = blockIdx.y * 128, n0 = blockIdx.x * 64;

    // DMA mapping: block-dma d writes 4 KB (32 rows); thread t -> row d*32+(t>>3),
    // LDS chunk (t&7); fetch global chunk (t&7)^((t>>3)&7).
    const int srow = t >> 3;
    const int schunk = (t & 7) ^ ((t >> 3) & 7);
    const int woff = w * 1024;
    const int rchunk = (n16 & 7);     // read-side XOR key = row&7 = n16&7

    floatx4 acc[4][2];
#pragma unroll
    for (int mt = 0; mt < 4; ++mt)
#pragma unroll
        for (int nt = 0; nt < 2; ++nt) acc[mt][nt] = (floatx4){0.f, 0.f, 0.f, 0.f};

    for (int k0 = 0; k0 < 512; k0 += 64) {
        __syncthreads();
#pragma unroll
        for (int d = 0; d < 4; ++d)
            dma16(xb + (size_t)(m0 + d * 32 + srow) * 512 + k0 + schunk * 8,
                  (char*)As + d * 4096 + woff);
#pragma unroll
        for (int d = 0; d < 2; ++d)
            dma16(wT + (size_t)(n0 + d * 32 + srow) * 512 + k0 + schunk * 8,
                  (char*)Bs + d * 4096 + woff);
        __syncthreads();
#pragma unroll
        for (int kh = 0; kh < 2; ++kh) {
            const int ch = (kh * 4 + quad) ^ rchunk;
            bf16x8 af[4], bf[2];
#pragma unroll
            for (int mt = 0; mt < 4; ++mt)
                af[mt] = *(const bf16x8*)(As + (wm * 64 + mt * 16 + n16) * 64 + ch * 8);
#pragma unroll
            for (int nt = 0; nt < 2; ++nt)
                bf[nt] = *(const bf16x8*)(Bs + (wn * 32 + nt * 16 + n16) * 64 + ch * 8);
#pragma unroll
            for (int mt = 0; mt < 4; ++mt)
#pragma unroll
                for (int nt = 0; nt < 2; ++nt)
                    acc[mt][nt] = mfma16(af[mt], bf[nt], acc[mt][nt]);
        }
    }

    // scatter epilogue (segment/h uniform per block)
#pragma unroll
    for (int mt = 0; mt < 4; ++mt)
#pragma unroll
        for (int nt = 0; nt < 2; ++nt)
#pragma unroll
            for (int r = 0; r < 4; ++r) {
                int m = m0 + wm * 64 + mt * 16 + quad * 4 + r;
                int n = n0 + wn * 32 + nt * 16 + n16;
                int b = m >> 11, i = m & 2047;
                int sg = n >> 9, cc = n & 511;
                int h = cc >> 6, d = cc & 63;
                size_t bh = (size_t)(b * NH + h);
                float fv = acc[mt][nt][r];
                if (sg == 0)      q[(bh * NN + i) * HD + d] = (__bf16)(fv * SCALE);
                else if (sg == 1) kk[(bh * NN + i) * HD + d] = (__bf16)fv;
                else              vT[(bh * HD + d) * NN + i] = (__bf16)fv;
            }
}

// ---------------------------------------------------------------------------
// Kernel D: flash attention, split-j x2, fixed softmax reference (m=0).
// Block = (b, h, 64 q-rows, jsplit), 4 waves; 16 j-iters of 64.
// ---------------------------------------------------------------------------
__global__ __launch_bounds__(256, 4) void flash_attn(const __bf16* __restrict__ qb,
                                                     const __bf16* __restrict__ kb,
                                                     const __bf16* __restrict__ vTb,
                                                     const __bf16* __restrict__ maskb,
                                                     __bf16* __restrict__ Opart,
                                                     float* __restrict__ lpart) {
    __shared__ __bf16 Ks[64][72];   // rows j-local, cols d
    __shared__ __bf16 Vs[64][72];   // rows d,       cols j-local
    __shared__ __bf16 Ps[64][72];   // rows i-local, cols j-local

    const int t = threadIdx.x;
    const int lane = t & 63;
    const int w = t >> 6;           // wave -> 16-row i-strip
    const int n16 = lane & 15;
    const int quad = lane >> 4;

    const int blk = blockIdx.x;
    const int split = blk & 1;
    const int it = (blk >> 1) & 31;
    const int h = (blk >> 6) & 7;
    const int b = blk >> 9;
    const int i0 = it * 64;
    const int bh = b * NH + h;

    bf16x8 qfrag[2];
    {
        const __bf16* qrow = qb + ((size_t)bh * NN + i0 + w * 16 + n16) * HD;
        qfrag[0] = *(const bf16x8*)(qrow + quad * 8);
        qfrag[1] = *(const bf16x8*)(qrow + 32 + quad * 8);
    }

    floatx4 O[4];
#pragma unroll
    for (int dt = 0; dt < 4; ++dt) O[dt] = (floatx4){0.f, 0.f, 0.f, 0.f};
    float lp = 0.f;

    const int srow = t >> 3, sseg = t & 7;
    const __bf16* kg = kb + (size_t)bh * NN * HD;
    const __bf16* vg = vTb + (size_t)bh * HD * NN;
    const __bf16* mbase = maskb + ((size_t)b * NN + i0 + w * 16 + n16) * NN;

    int j0 = split * (NN / 2);
    float4 k1 = *(const float4*)(kg + (size_t)(j0 + srow) * HD + sseg * 8);
    float4 k2 = *(const float4*)(kg + (size_t)(j0 + srow + 32) * HD + sseg * 8);
    float4 v1 = *(const float4*)(vg + (size_t)srow * NN + j0 + sseg * 8);
    float4 v2 = *(const float4*)(vg + (size_t)(srow + 32) * NN + j0 + sseg * 8);

    for (int iter = 0; iter < (NN / 2) / 64; ++iter, j0 += 64) {
        __syncthreads();
        *(float4*)(&Ks[srow][sseg * 8]) = k1;
        *(float4*)(&Ks[srow + 32][sseg * 8]) = k2;
        *(float4*)(&Vs[srow][sseg * 8]) = v1;
        *(float4*)(&Vs[srow + 32][sseg * 8]) = v2;
        __syncthreads();
        if (iter + 1 < (NN / 2) / 64) {
            int jn = j0 + 64;
            k1 = *(const float4*)(kg + (size_t)(jn + srow) * HD + sseg * 8);
            k2 = *(const float4*)(kg + (size_t)(jn + srow + 32) * HD + sseg * 8);
            v1 = *(const float4*)(vg + (size_t)srow * NN + jn + sseg * 8);
            v2 = *(const float4*)(vg + (size_t)(srow + 32) * NN + jn + sseg * 8);
        }
        ushort4 mu[4];
        const __bf16* mrow = mbase + j0 + quad * 4;
#pragma unroll
        for (int jt = 0; jt < 4; ++jt)
            mu[jt] = *(const ushort4*)(mrow + jt * 16);

        // S^T = K * Q^T: lane holds S[i=n16][j = jt*16 + quad*4 + r]
        floatx4 S[4];
#pragma unroll
        for (int jt = 0; jt < 4; ++jt) {
            floatx4 acc = (floatx4){0.f, 0.f, 0.f, 0.f};
            bf16x8 kf0 = *(const bf16x8*)(&Ks[jt * 16 + n16][quad * 8]);
            bf16x8 kf1 = *(const bf16x8*)(&Ks[jt * 16 + n16][32 + quad * 8]);
            acc = mfma16(kf0, qfrag[0], acc);
            acc = mfma16(kf1, qfrag[1], acc);
            S[jt] = acc;
        }

        // p = exp(mask * s); |s| <= ~0.05 so no max subtraction needed
#pragma unroll
        for (int jt = 0; jt < 4; ++jt) {
            float p0 = __expf(S[jt][0] * bf2f(mu[jt].x));
            float p1 = __expf(S[jt][1] * bf2f(mu[jt].y));
            float p2 = __expf(S[jt][2] * bf2f(mu[jt].z));
            float p3 = __expf(S[jt][3] * bf2f(mu[jt].w));
            lp += (p0 + p1) + (p2 + p3);
            bf16x4 pk;
            pk[0] = (__bf16)p0; pk[1] = (__bf16)p1;
            pk[2] = (__bf16)p2; pk[3] = (__bf16)p3;
            *(bf16x4*)(&Ps[w * 16 + n16][jt * 16 + quad * 4]) = pk;   // wave-local
        }

        bf16x8 pf0 = *(const bf16x8*)(&Ps[w * 16 + n16][quad * 8]);
        bf16x8 pf1 = *(const bf16x8*)(&Ps[w * 16 + n16][32 + quad * 8]);
#pragma unroll
        for (int dt = 0; dt < 4; ++dt) {
            bf16x8 vf0 = *(const bf16x8*)(&Vs[dt * 16 + n16][quad * 8]);
            bf16x8 vf1 = *(const bf16x8*)(&Vs[dt * 16 + n16][32 + quad * 8]);
            O[dt] = mfma16(pf0, vf0, O[dt]);
            O[dt] = mfma16(pf1, vf1, O[dt]);
        }
    }

    lp += __shfl_xor(lp, 16);
    lp += __shfl_xor(lp, 32);
    const size_t sb = (size_t)(split * BB * NH + bh);
    if (quad == 0)
        lpart[sb * NN + i0 + w * 16 + n16] = lp;
#pragma unroll
    for (int dt = 0; dt < 4; ++dt)
#pragma unroll
        for (int r = 0; r < 4; ++r) {
            int i = i0 + w * 16 + quad * 4 + r;
            int d = dt * 16 + n16;
            Opart[(sb * NN + i) * HD + d] = (__bf16)O[dt][r];
        }
}

// ---------------------------------------------------------------------------
// Kernel D2: combine 2 splits -> ohb [b, n, h*d] bf16
// ---------------------------------------------------------------------------
__global__ __launch_bounds__(256) void combine(const __bf16* __restrict__ Opart,
                                               const float* __restrict__ lpart,
                                               __bf16* __restrict__ ohb) {
    int g = blockIdx.x * 256 + threadIdx.x;
    int d0 = (g & 7) * 8;
    int n = (g >> 3) & 2047;
    int bh = g >> 14;                            // 0..15
    int b = bh >> 3, h = bh & 7;
    size_t idx0 = ((size_t)bh * NN + n) * HD + d0;
    size_t idx1 = ((size_t)(BB * NH + bh) * NN + n) * HD + d0;
    bf16x8 o0 = *(const bf16x8*)(Opart + idx0);
    bf16x8 o1 = *(const bf16x8*)(Opart + idx1);
    float l = lpart[(size_t)bh * NN + n] + lpart[(size_t)(BB * NH + bh) * NN + n];
    float inv = 1.0f / l;
    bf16x8 r;
#pragma unroll
    for (int e = 0; e < 8; ++e)
        r[e] = (__bf16)(((float)o0[e] + (float)o1[e]) * inv);
    *(bf16x8*)(ohb + ((size_t)b * NN + n) * (NH * HD) + h * HD + d0) = r;
}

// ---------------------------------------------------------------------------
// Kernel E: out = ohb @ w_out + b_out via MFMA + DMA staging.
// BM=64, BN=64, BK=64; grid (8,64)=512 blocks (2/CU even); 4 waves (2x2).
// ---------------------------------------------------------------------------
__global__ __launch_bounds__(256) void out_mfma(const __bf16* __restrict__ A,
                                                const __bf16* __restrict__ wT,
                                                const float* __restrict__ bias,
                                                float* __restrict__ out) {
    __shared__ __bf16 As[64 * 64];    // 8 KB
    __shared__ __bf16 Bs[64 * 64];    // 8 KB
    const int t = threadIdx.x;
    const int lane = t & 63, w = t >> 6;
    const int n16 = lane & 15, quad = lane >> 4;
    const int wm = w >> 1, wn = w & 1;     // wave tile: 32 x 32
    const int m0 = blockIdx.y * 64, n0 = blockIdx.x * 64;

    const int srow = t >> 3;
    const int schunk = (t & 7) ^ ((t >> 3) & 7);
    const int woff = w * 1024;
    const int rchunk = (n16 & 7);

    floatx4 acc[2][2];
#pragma unroll
    for (int mt = 0; mt < 2; ++mt)
#pragma unroll
        for (int nt = 0; nt < 2; ++nt) acc[mt][nt] = (floatx4){0.f, 0.f, 0.f, 0.f};

    for (int k0 = 0; k0 < 512; k0 += 64) {
        __syncthreads();
#pragma unroll
        for (int d = 0; d < 2; ++d)
            dma16(A + (size_t)(m0 + d * 32 + srow) * 512 + k0 + schunk * 8,
                  (char*)As + d * 4096 + woff);
#pragma unroll
        for (int d = 0; d < 2; ++d)
            dma16(wT + (size_t)(n0 + d * 32 + srow) * 512 + k0 + schunk * 8,
                  (char*)Bs + d * 4096 + woff);
        __syncthreads();
#pragma unroll
        for (int kh = 0; kh < 2; ++kh) {
            const int ch = (kh * 4 + quad) ^ rchunk;
            bf16x8 af[2], bf[2];
#pragma unroll
            for (int mt = 0; mt < 2; ++mt)
                af[mt] = *(const bf16x8*)(As + (wm * 32 + mt * 16 + n16) * 64 + ch * 8);
#pragma unroll
            for (int nt = 0; nt < 2; ++nt)
                bf[nt] = *(const bf16x8*)(Bs + (wn * 32 + nt * 16 + n16) * 64 + ch * 8);
#pragma unroll
            for (int mt = 0; mt < 2; ++mt)
#pragma unroll
                for (int nt = 0; nt < 2; ++nt)
                    acc[mt][nt] = mfma16(af[mt], bf[nt], acc[mt][nt]);
        }
    }

#pragma unroll
    for (int mt = 0; mt < 2; ++mt)
#pragma unroll
        for (int nt = 0; nt < 2; ++nt)
#pragma unroll
            for (int r = 0; r < 4; ++r) {
                int m = m0 + wm * 32 + mt * 16 + quad * 4 + r;
                int n = n0 + wn * 32 + nt * 16 + n16;
                out[(size_t)m * 512 + n] = acc[mt][nt][r] + bias[n];
            }
}

extern "C" void kernel_launch(void* const* d_in, const int* in_sizes, int n_in,
                              void* d_out, int out_size, void* d_ws, size_t ws_size,
                              hipStream_t stream) {
    const float* x     = (const float*)d_in[0];
    const float* adj   = (const float*)d_in[1];
    const float* w_qkv = (const float*)d_in[2];
    const float* w_out = (const float*)d_in[3];
    const float* b_out = (const float*)d_in[4];
    float* out = (float*)d_out;
    char* wsb = (char*)d_ws;

    // workspace byte layout
    __bf16* wqkvT = (__bf16*)(wsb + 0);                  // 1.5 MiB
    __bf16* woutT = (__bf16*)(wsb + (3u << 19));         // 0.5 MiB
    __bf16* q     = (__bf16*)(wsb + (2u << 20));         // 4 MiB
    __bf16* ohb   = (__bf16*)(wsb + (2u << 20));         // aliases q (q dead at combine)
    __bf16* k     = (__bf16*)(wsb + (6u << 20));         // 4 MiB
    __bf16* vT    = (__bf16*)(wsb + (10u << 20));        // 4 MiB
    __bf16* mask  = (__bf16*)(wsb + (14u << 20));        // 16 MiB
    __bf16* Opart = (__bf16*)(wsb + (30u << 20));        // 8 MiB (2 splits)
    __bf16* xb    = (__bf16*)(wsb + (30u << 20));        // aliases Opart (dead after qkv)
    float*  lpart = (float*) (wsb + (46u << 20));        // 256 KiB

    adj_softmax<<<BB * NN, 256, 0, stream>>>(adj, mask);
    xcast<<<1024, 256, 0, stream>>>(x, xb);
    tcast_w<<<dim3(1536 / 32, 512 / 32), 256, 0, stream>>>(w_qkv, wqkvT, 512, 1536);
    tcast_w<<<dim3(512 / 32, 512 / 32), 256, 0, stream>>>(w_out, woutT, 512, 512);
    qkv_mfma<<<dim3(1536 / 64, 4096 / 128), 256, 0, stream>>>(xb, wqkvT, q, k, vT);
    flash_attn<<<BB * NH * 32 * 2, 256, 0, stream>>>(q, k, vT, mask, Opart, lpart);
    combine<<<1024, 256, 0, stream>>>(Opart, lpart, ohb);
    out_mfma<<<dim3(512 / 64, 4096 / 64), 256, 0, stream>>>(ohb, woutT, b_out, out);
}

// Round 7
// 163.081 us; speedup vs baseline: 4.1518x; 1.0154x over previous
//
#include <hip/hip_runtime.h>
#include <hip/hip_bf16.h>
#include <math.h>

// Problem constants
#define BB 2
#define NN 2048
#define DIM 512
#define NH 8
#define HD 64
#define SCALE 0.125f

typedef __bf16 bf16x8 __attribute__((ext_vector_type(8)));
typedef __bf16 bf16x4 __attribute__((ext_vector_type(4)));
typedef float floatx4 __attribute__((ext_vector_type(4)));

static inline __device__ floatx4 mfma16(bf16x8 a, bf16x8 b, floatx4 c) {
    return __builtin_amdgcn_mfma_f32_16x16x32_bf16(a, b, c, 0, 0, 0);
}

static inline __device__ bf16x8 cvt8(float4 a, float4 b) {
    bf16x8 r;
    r[0] = (__bf16)a.x; r[1] = (__bf16)a.y; r[2] = (__bf16)a.z; r[3] = (__bf16)a.w;
    r[4] = (__bf16)b.x; r[5] = (__bf16)b.y; r[6] = (__bf16)b.z; r[7] = (__bf16)b.w;
    return r;
}

static inline __device__ float bf2f(unsigned short u) {
    return __uint_as_float(((unsigned)u) << 16);
}

// async global->LDS, 16 B per lane; lds base must be wave-uniform
static inline __device__ void dma16(const void* g, void* l) {
    __builtin_amdgcn_global_load_lds(
        (const __attribute__((address_space(1))) unsigned int*)g,
        (__attribute__((address_space(3))) unsigned int*)l,
        16, 0, 0);
}

// ---------------------------------------------------------------------------
// Kernel 1: prep — fused adj_softmax + xcast + two weight transpose-casts.
// Heterogeneous grid, block-uniform branch:
//   [0,4096):      adj softmax rows -> bf16 mask
//   [4096,5120):   x fp32 -> bf16
//   [5120,5888):   w_qkv [512][1536] -> wqkvT [1536][512] bf16
//   [5888,6144):   w_out [512][512]  -> woutT [512][512] bf16
// ---------------------------------------------------------------------------
__global__ __launch_bounds__(256) void prep(const float* __restrict__ adj,
                                            __bf16* __restrict__ mask,
                                            const float* __restrict__ x,
                                            __bf16* __restrict__ xb,
                                            const float* __restrict__ w_qkv,
                                            __bf16* __restrict__ wqkvT,
                                            const float* __restrict__ w_out,
                                            __bf16* __restrict__ woutT) {
    __shared__ __align__(16) float smem[32][33];
    const int blk = blockIdx.x;
    const int t = threadIdx.x;

    if (blk < 4096) {
        // ---- adj softmax (row = blk) ----
        const float* a = adj + (size_t)blk * NN;
        __bf16* m = mask + (size_t)blk * NN;
        int w = t >> 6, lane = t & 63;
        float4 va = *(const float4*)(a + 4 * t);
        float4 vb = *(const float4*)(a + 1024 + 4 * t);
        float v[8] = {va.x, va.y, va.z, va.w, vb.x, vb.y, vb.z, vb.w};
        float mx = -INFINITY;
#pragma unroll
        for (int c = 0; c < 8; ++c) mx = fmaxf(mx, v[c]);
#pragma unroll
        for (int s = 1; s < 64; s <<= 1) mx = fmaxf(mx, __shfl_xor(mx, s));
        float* red = &smem[0][0];
        if (lane == 0) red[w] = mx;
        __syncthreads();
        mx = fmaxf(fmaxf(red[0], red[1]), fmaxf(red[2], red[3]));
        float sm = 0.f;
        float e[8];
#pragma unroll
        for (int c = 0; c < 8; ++c) { e[c] = __expf(v[c] - mx); sm += e[c]; }
#pragma unroll
        for (int s = 1; s < 64; s <<= 1) sm += __shfl_xor(sm, s);
        if (lane == 0) red[4 + w] = sm;
        __syncthreads();
        float inv = 1.0f / ((red[4] + red[5]) + (red[6] + red[7]));
        bf16x4 o0, o1;
#pragma unroll
        for (int c = 0; c < 4; ++c) {
            o0[c] = (__bf16)(e[c] * inv);
            o1[c] = (__bf16)(e[c + 4] * inv);
        }
        *(bf16x4*)(m + 4 * t) = o0;
        *(bf16x4*)(m + 1024 + 4 * t) = o1;
    } else if (blk < 5120) {
        // ---- xcast ----
        int g = (blk - 4096) * 256 + t;
        float4 f0 = ((const float4*)x)[2 * (size_t)g];
        float4 f1 = ((const float4*)x)[2 * (size_t)g + 1];
        *(bf16x8*)(xb + 8 * (size_t)g) = cvt8(f0, f1);
    } else {
        // ---- weight transpose-cast ----
        const float* w; __bf16* wT; int K, N, bx, by;
        if (blk < 5888) {
            int idx = blk - 5120;
            w = w_qkv; wT = wqkvT; K = 512; N = 1536;
            bx = idx % 48; by = idx / 48;
        } else {
            int idx = blk - 5888;
            w = w_out; wT = woutT; K = 512; N = 512;
            bx = idx % 16; by = idx / 16;
        }
        int n0 = bx * 32, k0 = by * 32;
        int c = t & 31, r = t >> 5;
#pragma unroll
        for (int p = 0; p < 4; ++p)
            smem[r + p * 8][c] = w[(size_t)(k0 + r + p * 8) * N + n0 + c];
        __syncthreads();
#pragma unroll
        for (int p = 0; p < 4; ++p)
            wT[(size_t)(n0 + r + p * 8) * K + k0 + c] = (__bf16)smem[c][r + p * 8];
    }
}

// ---------------------------------------------------------------------------
// Kernel 2: qkv = xb @ w_qkv via MFMA + DMA staging.
// BM=128, BN=64, BK=64; grid (24,32)=768 blocks; 4 waves (2x2).
// 128 B LDS rows; XOR swizzle key (row&7). q gets SCALE folded in.
// ---------------------------------------------------------------------------
__global__ __launch_bounds__(256) void qkv_mfma(const __bf16* __restrict__ xb,
                                                const __bf16* __restrict__ wT,
                                                __bf16* __restrict__ q,
                                                __bf16* __restrict__ kk,
                                                __bf16* __restrict__ vT) {
    __shared__ __bf16 As[128 * 64];   // 16 KB
    __shared__ __bf16 Bs[64 * 64];    // 8 KB
    const int t = threadIdx.x;
    const int lane = t & 63, w = t >> 6;
    const int n16 = lane & 15, quad = lane >> 4;
    const int wm = w >> 1, wn = w & 1;
    const int m0 = blockIdx.y * 128, n0 = blockIdx.x * 64;

    const int srow = t >> 3;
    const int schunk = (t & 7) ^ ((t >> 3) & 7);
    const int woff = w * 1024;
    const int rchunk = (n16 & 7);

    floatx4 acc[4][2];
#pragma unroll
    for (int mt = 0; mt < 4; ++mt)
#pragma unroll
        for (int nt = 0; nt < 2; ++nt) acc[mt][nt] = (floatx4){0.f, 0.f, 0.f, 0.f};

    for (int k0 = 0; k0 < 512; k0 += 64) {
        __syncthreads();
#pragma unroll
        for (int d = 0; d < 4; ++d)
            dma16(xb + (size_t)(m0 + d * 32 + srow) * 512 + k0 + schunk * 8,
                  (char*)As + d * 4096 + woff);
#pragma unroll
        for (int d = 0; d < 2; ++d)
            dma16(wT + (size_t)(n0 + d * 32 + srow) * 512 + k0 + schunk * 8,
                  (char*)Bs + d * 4096 + woff);
        __syncthreads();
#pragma unroll
        for (int kh = 0; kh < 2; ++kh) {
            const int ch = (kh * 4 + quad) ^ rchunk;
            bf16x8 af[4], bf[2];
#pragma unroll
            for (int mt = 0; mt < 4; ++mt)
                af[mt] = *(const bf16x8*)(As + (wm * 64 + mt * 16 + n16) * 64 + ch * 8);
#pragma unroll
            for (int nt = 0; nt < 2; ++nt)
                bf[nt] = *(const bf16x8*)(Bs + (wn * 32 + nt * 16 + n16) * 64 + ch * 8);
#pragma unroll
            for (int mt = 0; mt < 4; ++mt)
#pragma unroll
                for (int nt = 0; nt < 2; ++nt)
                    acc[mt][nt] = mfma16(af[mt], bf[nt], acc[mt][nt]);
        }
    }

#pragma unroll
    for (int mt = 0; mt < 4; ++mt)
#pragma unroll
        for (int nt = 0; nt < 2; ++nt)
#pragma unroll
            for (int r = 0; r < 4; ++r) {
                int m = m0 + wm * 64 + mt * 16 + quad * 4 + r;
                int n = n0 + wn * 32 + nt * 16 + n16;
                int b = m >> 11, i = m & 2047;
                int sg = n >> 9, cc = n & 511;
                int h = cc >> 6, d = cc & 63;
                size_t bh = (size_t)(b * NH + h);
                float fv = acc[mt][nt][r];
                if (sg == 0)      q[(bh * NN + i) * HD + d] = (__bf16)(fv * SCALE);
                else if (sg == 1) kk[(bh * NN + i) * HD + d] = (__bf16)fv;
                else              vT[(bh * HD + d) * NN + i] = (__bf16)fv;
            }
}

// ---------------------------------------------------------------------------
// Kernel 3: flash attention, split-j x2, fixed softmax reference (m=0).
// Block = (b, h, 64 q-rows, jsplit), 4 waves; 16 j-iters of 64.
// ---------------------------------------------------------------------------
__global__ __launch_bounds__(256, 4) void flash_attn(const __bf16* __restrict__ qb,
                                                     const __bf16* __restrict__ kb,
                                                     const __bf16* __restrict__ vTb,
                                                     const __bf16* __restrict__ maskb,
                                                     __bf16* __restrict__ Opart,
                                                     float* __restrict__ lpart) {
    __shared__ __bf16 Ks[64][72];
    __shared__ __bf16 Vs[64][72];
    __shared__ __bf16 Ps[64][72];

    const int t = threadIdx.x;
    const int lane = t & 63;
    const int w = t >> 6;
    const int n16 = lane & 15;
    const int quad = lane >> 4;

    const int blk = blockIdx.x;
    const int split = blk & 1;
    const int it = (blk >> 1) & 31;
    const int h = (blk >> 6) & 7;
    const int b = blk >> 9;
    const int i0 = it * 64;
    const int bh = b * NH + h;

    bf16x8 qfrag[2];
    {
        const __bf16* qrow = qb + ((size_t)bh * NN + i0 + w * 16 + n16) * HD;
        qfrag[0] = *(const bf16x8*)(qrow + quad * 8);
        qfrag[1] = *(const bf16x8*)(qrow + 32 + quad * 8);
    }

    floatx4 O[4];
#pragma unroll
    for (int dt = 0; dt < 4; ++dt) O[dt] = (floatx4){0.f, 0.f, 0.f, 0.f};
    float lp = 0.f;

    const int srow = t >> 3, sseg = t & 7;
    const __bf16* kg = kb + (size_t)bh * NN * HD;
    const __bf16* vg = vTb + (size_t)bh * HD * NN;
    const __bf16* mbase = maskb + ((size_t)b * NN + i0 + w * 16 + n16) * NN;

    int j0 = split * (NN / 2);
    float4 k1 = *(const float4*)(kg + (size_t)(j0 + srow) * HD + sseg * 8);
    float4 k2 = *(const float4*)(kg + (size_t)(j0 + srow + 32) * HD + sseg * 8);
    float4 v1 = *(const float4*)(vg + (size_t)srow * NN + j0 + sseg * 8);
    float4 v2 = *(const float4*)(vg + (size_t)(srow + 32) * NN + j0 + sseg * 8);

    for (int iter = 0; iter < (NN / 2) / 64; ++iter, j0 += 64) {
        __syncthreads();
        *(float4*)(&Ks[srow][sseg * 8]) = k1;
        *(float4*)(&Ks[srow + 32][sseg * 8]) = k2;
        *(float4*)(&Vs[srow][sseg * 8]) = v1;
        *(float4*)(&Vs[srow + 32][sseg * 8]) = v2;
        __syncthreads();
        if (iter + 1 < (NN / 2) / 64) {
            int jn = j0 + 64;
            k1 = *(const float4*)(kg + (size_t)(jn + srow) * HD + sseg * 8);
            k2 = *(const float4*)(kg + (size_t)(jn + srow + 32) * HD + sseg * 8);
            v1 = *(const float4*)(vg + (size_t)srow * NN + jn + sseg * 8);
            v2 = *(const float4*)(vg + (size_t)(srow + 32) * NN + jn + sseg * 8);
        }
        ushort4 mu[4];
        const __bf16* mrow = mbase + j0 + quad * 4;
#pragma unroll
        for (int jt = 0; jt < 4; ++jt)
            mu[jt] = *(const ushort4*)(mrow + jt * 16);

        floatx4 S[4];
#pragma unroll
        for (int jt = 0; jt < 4; ++jt) {
            floatx4 acc = (floatx4){0.f, 0.f, 0.f, 0.f};
            bf16x8 kf0 = *(const bf16x8*)(&Ks[jt * 16 + n16][quad * 8]);
            bf16x8 kf1 = *(const bf16x8*)(&Ks[jt * 16 + n16][32 + quad * 8]);
            acc = mfma16(kf0, qfrag[0], acc);
            acc = mfma16(kf1, qfrag[1], acc);
            S[jt] = acc;
        }

#pragma unroll
        for (int jt = 0; jt < 4; ++jt) {
            float p0 = __expf(S[jt][0] * bf2f(mu[jt].x));
            float p1 = __expf(S[jt][1] * bf2f(mu[jt].y));
            float p2 = __expf(S[jt][2] * bf2f(mu[jt].z));
            float p3 = __expf(S[jt][3] * bf2f(mu[jt].w));
            lp += (p0 + p1) + (p2 + p3);
            bf16x4 pk;
            pk[0] = (__bf16)p0; pk[1] = (__bf16)p1;
            pk[2] = (__bf16)p2; pk[3] = (__bf16)p3;
            *(bf16x4*)(&Ps[w * 16 + n16][jt * 16 + quad * 4]) = pk;
        }

        bf16x8 pf0 = *(const bf16x8*)(&Ps[w * 16 + n16][quad * 8]);
        bf16x8 pf1 = *(const bf16x8*)(&Ps[w * 16 + n16][32 + quad * 8]);
#pragma unroll
        for (int dt = 0; dt < 4; ++dt) {
            bf16x8 vf0 = *(const bf16x8*)(&Vs[dt * 16 + n16][quad * 8]);
            bf16x8 vf1 = *(const bf16x8*)(&Vs[dt * 16 + n16][32 + quad * 8]);
            O[dt] = mfma16(pf0, vf0, O[dt]);
            O[dt] = mfma16(pf1, vf1, O[dt]);
        }
    }

    lp += __shfl_xor(lp, 16);
    lp += __shfl_xor(lp, 32);
    const size_t sb = (size_t)(split * BB * NH + bh);
    if (quad == 0)
        lpart[sb * NN + i0 + w * 16 + n16] = lp;
#pragma unroll
    for (int dt = 0; dt < 4; ++dt)
#pragma unroll
        for (int r = 0; r < 4; ++r) {
            int i = i0 + w * 16 + quad * 4 + r;
            int d = dt * 16 + n16;
            Opart[(sb * NN + i) * HD + d] = (__bf16)O[dt][r];
        }
}

// ---------------------------------------------------------------------------
// Kernel 4: out = combine(Opart,lpart) @ w_out + b_out, fused.
// BM=64, BN=64, BK=64; grid (8,64)=512 blocks; 4 waves (2x2).
// A-tile built in-register from the two splits (k-chunk = one head since BK=HD).
// ---------------------------------------------------------------------------
__global__ __launch_bounds__(256) void out_mfma(const __bf16* __restrict__ Opart,
                                                const float* __restrict__ lpart,
                                                const __bf16* __restrict__ wT,
                                                const float* __restrict__ bias,
                                                float* __restrict__ out) {
    __shared__ __bf16 As[64 * 64];    // 8 KB
    __shared__ __bf16 Bs[64 * 64];    // 8 KB
    const int t = threadIdx.x;
    const int lane = t & 63, w = t >> 6;
    const int n16 = lane & 15, quad = lane >> 4;
    const int wm = w >> 1, wn = w & 1;
    const int m0 = blockIdx.y * 64, n0 = blockIdx.x * 64;

    const int srow = t >> 3;            // 0..31
    const int cg = t & 7;               // global k-chunk (8 bf16)
    const int schunk = cg ^ (srow & 7); // B dma swizzle
    const int woff = w * 1024;
    const int rchunk = (n16 & 7);

    floatx4 acc[2][2];
#pragma unroll
    for (int mt = 0; mt < 2; ++mt)
#pragma unroll
        for (int nt = 0; nt < 2; ++nt) acc[mt][nt] = (floatx4){0.f, 0.f, 0.f, 0.f};

    for (int k0 = 0; k0 < 512; k0 += 64) {
        const int h = k0 >> 6;
        // build combined A rows R1=srow, R2=srow+32 (chunk cg)
        const int m1 = m0 + srow, m2 = m0 + srow + 32;
        const int b1 = m1 >> 11, nn1 = m1 & 2047;
        const int b2 = m2 >> 11, nn2 = m2 & 2047;
        const size_t sb1 = (size_t)(b1 * NH + h);
        const size_t sb2 = (size_t)(b2 * NH + h);
        bf16x8 o1a = *(const bf16x8*)(Opart + (sb1 * NN + nn1) * HD + cg * 8);
        bf16x8 o1b = *(const bf16x8*)(Opart + ((sb1 + BB * NH) * NN + nn1) * HD + cg * 8);
        bf16x8 o2a = *(const bf16x8*)(Opart + (sb2 * NN + nn2) * HD + cg * 8);
        bf16x8 o2b = *(const bf16x8*)(Opart + ((sb2 + BB * NH) * NN + nn2) * HD + cg * 8);
        float i1 = 1.0f / (lpart[sb1 * NN + nn1] + lpart[(sb1 + BB * NH) * NN + nn1]);
        float i2 = 1.0f / (lpart[sb2 * NN + nn2] + lpart[(sb2 + BB * NH) * NN + nn2]);
        bf16x8 a1, a2;
#pragma unroll
        for (int e = 0; e < 8; ++e) {
            a1[e] = (__bf16)(((float)o1a[e] + (float)o1b[e]) * i1);
            a2[e] = (__bf16)(((float)o2a[e] + (float)o2b[e]) * i2);
        }
        __syncthreads();
        *(bf16x8*)(As + srow * 64 + (cg ^ (srow & 7)) * 8) = a1;
        *(bf16x8*)(As + (srow + 32) * 64 + (cg ^ ((srow + 32) & 7)) * 8) = a2;
        dma16(wT + (size_t)(n0 + srow) * 512 + k0 + schunk * 8, (char*)Bs + woff);
        dma16(wT + (size_t)(n0 + 32 + srow) * 512 + k0 + schunk * 8,
              (char*)Bs + 4096 + woff);
        __syncthreads();
#pragma unroll
        for (int kh = 0; kh < 2; ++kh) {
            const int ch = (kh * 4 + quad) ^ rchunk;
            bf16x8 af[2], bf[2];
#pragma unroll
            for (int mt = 0; mt < 2; ++mt)
                af[mt] = *(const bf16x8*)(As + (wm * 32 + mt * 16 + n16) * 64 + ch * 8);
#pragma unroll
            for (int nt = 0; nt < 2; ++nt)
                bf[nt] = *(const bf16x8*)(Bs + (wn * 32 + nt * 16 + n16) * 64 + ch * 8);
#pragma unroll
            for (int mt = 0; mt < 2; ++mt)
#pragma unroll
                for (int nt = 0; nt < 2; ++nt)
                    acc[mt][nt] = mfma16(af[mt], bf[nt], acc[mt][nt]);
        }
    }

#pragma unroll
    for (int mt = 0; mt < 2; ++mt)
#pragma unroll
        for (int nt = 0; nt < 2; ++nt)
#pragma unroll
            for (int r = 0; r < 4; ++r) {
                int m = m0 + wm * 32 + mt * 16 + quad * 4 + r;
                int n = n0 + wn * 32 + nt * 16 + n16;
                out[(size_t)m * 512 + n] = acc[mt][nt][r] + bias[n];
            }
}

extern "C" void kernel_launch(void* const* d_in, const int* in_sizes, int n_in,
                              void* d_out, int out_size, void* d_ws, size_t ws_size,
                              hipStream_t stream) {
    const float* x     = (const float*)d_in[0];
    const float* adj   = (const float*)d_in[1];
    const float* w_qkv = (const float*)d_in[2];
    const float* w_out = (const float*)d_in[3];
    const float* b_out = (const float*)d_in[4];
    float* out = (float*)d_out;
    char* wsb = (char*)d_ws;

    // workspace byte layout
    __bf16* wqkvT = (__bf16*)(wsb + 0);                  // 1.5 MiB
    __bf16* woutT = (__bf16*)(wsb + (3u << 19));         // 0.5 MiB
    __bf16* q     = (__bf16*)(wsb + (2u << 20));         // 4 MiB
    __bf16* k     = (__bf16*)(wsb + (6u << 20));         // 4 MiB
    __bf16* vT    = (__bf16*)(wsb + (10u << 20));        // 4 MiB
    __bf16* mask  = (__bf16*)(wsb + (14u << 20));        // 16 MiB
    __bf16* Opart = (__bf16*)(wsb + (30u << 20));        // 8 MiB (2 splits)
    __bf16* xb    = (__bf16*)(wsb + (38u << 20));        // 4 MiB
    float*  lpart = (float*) (wsb + (42u << 20));        // 256 KiB

    prep<<<6144, 256, 0, stream>>>(adj, mask, x, xb, w_qkv, wqkvT, w_out, woutT);
    qkv_mfma<<<dim3(1536 / 64, 4096 / 128), 256, 0, stream>>>(xb, wqkvT, q, k, vT);
    flash_attn<<<BB * NH * 32 * 2, 256, 0, stream>>>(q, k, vT, mask, Opart, lpart);
    out_mfma<<<dim3(512 / 64, 4096 / 64), 256, 0, stream>>>(Opart, lpart, woutT, b_out, out);
}